// Round 1
// baseline (1258.680 us; speedup 1.0000x reference)
//
#include <hip/hip_runtime.h>
#include <hip/hip_bf16.h>
#include <cmath>

#define N_TOK 8192
#define CDIM  768
#define HDIM  3072
#define NEXP  8

typedef __bf16 bf16;
typedef __bf16 bf16x4 __attribute__((ext_vector_type(4)));
typedef __bf16 bf16x8 __attribute__((ext_vector_type(8)));
typedef float  f32x4  __attribute__((ext_vector_type(4)));

// ---------------------------------------------------------------------------
// Router: logits = x @ Wr, softmax, top-1 argmax (first-max), bucket scatter,
// importance partial sums.
// ---------------------------------------------------------------------------
__global__ __launch_bounds__(128) void router_kernel(
    const float* __restrict__ x, const float* __restrict__ Wr,
    float* __restrict__ tprob, int* __restrict__ bucket,
    int* __restrict__ counts, float* __restrict__ importance)
{
  __shared__ float wr_l[CDIM * NEXP];   // [c][e], 24 KB
  __shared__ float xs[128][33];         // padded, 16.9 KB
  __shared__ float imp_l[2][NEXP];

  const int tid  = threadIdx.x;
  const int lane = tid & 63;
  const int wv   = tid >> 6;
  const int tok0 = blockIdx.x * 128;

  for (int i = tid; i < CDIM * NEXP; i += 128) wr_l[i] = Wr[i];

  float acc[NEXP];
  #pragma unroll
  for (int e2 = 0; e2 < NEXP; ++e2) acc[e2] = 0.0f;

  for (int ch = 0; ch < CDIM / 32; ++ch) {
    __syncthreads();
    #pragma unroll
    for (int i = 0; i < 8; ++i) {
      int lin = i * 128 + tid;          // 0..1023 float4s
      int row = lin >> 3;               // 8 float4 per row-chunk
      int c4  = lin & 7;
      const float4 v = *(const float4*)(x + (size_t)(tok0 + row) * CDIM + ch * 32 + c4 * 4);
      xs[row][c4 * 4 + 0] = v.x;
      xs[row][c4 * 4 + 1] = v.y;
      xs[row][c4 * 4 + 2] = v.z;
      xs[row][c4 * 4 + 3] = v.w;
    }
    __syncthreads();
    #pragma unroll
    for (int c = 0; c < 32; ++c) {
      float xv = xs[tid][c];
      const float* w = &wr_l[(ch * 32 + c) * NEXP];
      #pragma unroll
      for (int e2 = 0; e2 < NEXP; ++e2) acc[e2] = fmaf(xv, w[e2], acc[e2]);
    }
  }

  // softmax + argmax (strict > keeps FIRST max, matching jnp.argmax)
  float m = acc[0]; int be = 0;
  #pragma unroll
  for (int e2 = 1; e2 < NEXP; ++e2) if (acc[e2] > m) { m = acc[e2]; be = e2; }
  float pr[NEXP]; float s = 0.0f;
  #pragma unroll
  for (int e2 = 0; e2 < NEXP; ++e2) { pr[e2] = expf(acc[e2] - m); s += pr[e2]; }
  const float inv = 1.0f / s;
  const int tok = tok0 + tid;
  tprob[tok] = pr[be] * inv;

  // importance: wave butterfly reduce, then block combine
  #pragma unroll
  for (int e2 = 0; e2 < NEXP; ++e2) {
    float v = pr[e2] * inv;
    #pragma unroll
    for (int off = 1; off < 64; off <<= 1) v += __shfl_xor(v, off);
    if (lane == 0) imp_l[wv][e2] = v;
  }

  // bucket scatter: per-wave ballot aggregation (8 atomics per wave total)
  for (int e2 = 0; e2 < NEXP; ++e2) {
    unsigned long long msk = __ballot(be == e2);
    if (msk) {
      int leader = __builtin_ctzll(msk);
      int cnt    = __popcll(msk);
      int base   = 0;
      if (lane == leader) base = atomicAdd(&counts[e2], cnt);
      base = __shfl(base, leader);
      if (be == e2) {
        int rank = __popcll(msk & ((1ull << lane) - 1ull));
        bucket[e2 * N_TOK + base + rank] = tok;
      }
    }
  }

  __syncthreads();
  if (tid < NEXP) atomicAdd(&importance[tid], imp_l[0][tid] + imp_l[1][tid]);
}

// ---------------------------------------------------------------------------
// aux_loss = E * sum_e (importance_e/n) * (count_e/n)
// ---------------------------------------------------------------------------
__global__ void aux_kernel(const int* __restrict__ counts,
                           const float* __restrict__ importance,
                           float* __restrict__ out_aux)
{
  if (threadIdx.x == 0) {
    float s = 0.0f;
    for (int e2 = 0; e2 < NEXP; ++e2) s += importance[e2] * (float)counts[e2];
    out_aux[0] = (float)NEXP * s / ((float)N_TOK * (float)N_TOK);
  }
}

// ---------------------------------------------------------------------------
// FFN1: h[token] = gelu_exact(x[token] @ W1[e] + b1[e])  (grouped by expert)
// 128x128 tile, BK=64, 4 waves, mfma_f32_16x16x32_bf16.
// ---------------------------------------------------------------------------
__global__ __launch_bounds__(256) void ffn1_kernel(
    const float* __restrict__ x, const float* __restrict__ W1,
    const float* __restrict__ b1, const int* __restrict__ counts,
    const int* __restrict__ bucket, bf16* __restrict__ hbuf)
{
  const int e   = blockIdx.z;
  const int cnt = counts[e];
  const int m0  = blockIdx.x * 128;
  if (m0 >= cnt) return;
  const int n0  = blockIdx.y * 128;

  const int tid  = threadIdx.x;
  const int lane = tid & 63;
  const int wv   = tid >> 6;
  const int wr   = (wv >> 1) * 64;
  const int wc   = (wv & 1) * 64;

  __shared__ __attribute__((aligned(16))) bf16 As[128 * 64];
  __shared__ __attribute__((aligned(16))) bf16 Bs[128 * 64];   // stored [n][k]

  const int* buck = bucket + e * N_TOK;
  const float* W  = W1 + (size_t)e * CDIM * HDIM;

  f32x4 acc[4][4];
  #pragma unroll
  for (int i = 0; i < 4; ++i)
    #pragma unroll
    for (int j = 0; j < 4; ++j)
      #pragma unroll
      for (int q = 0; q < 4; ++q) acc[i][j][q] = 0.0f;

  for (int k0 = 0; k0 < CDIM; k0 += 64) {
    __syncthreads();
    // ---- stage A: gathered x rows, fp32 -> bf16, XOR-swizzled
    #pragma unroll
    for (int i = 0; i < 8; ++i) {
      int lin = i * 256 + tid;
      int row = lin >> 4;               // 16 float4 per 64-float row
      int c4  = lin & 15;
      int gm  = m0 + row;
      float4 v = make_float4(0.f, 0.f, 0.f, 0.f);
      if (gm < cnt)
        v = *(const float4*)(x + (size_t)buck[gm] * CDIM + k0 + c4 * 4);
      bf16x4 bv;
      bv[0] = (bf16)v.x; bv[1] = (bf16)v.y; bv[2] = (bf16)v.z; bv[3] = (bf16)v.w;
      int byte = row * 128 + c4 * 8;
      byte ^= (row & 7) << 4;
      *(bf16x4*)((char*)As + byte) = bv;
    }
    // ---- stage B: W1 tile [k][n] -> Bs[n][k] via 4x4 register micro-transpose
    #pragma unroll
    for (int r = 0; r < 2; ++r) {
      int ng = tid & 31;
      int kg = (tid >> 5) + r * 8;
      const float* gp = W + (size_t)(k0 + kg * 4) * HDIM + n0 + ng * 4;
      float4 v0 = *(const float4*)(gp);
      float4 v1 = *(const float4*)(gp + HDIM);
      float4 v2 = *(const float4*)(gp + 2 * HDIM);
      float4 v3 = *(const float4*)(gp + 3 * HDIM);
      float c0[4] = {v0.x, v0.y, v0.z, v0.w};
      float c1[4] = {v1.x, v1.y, v1.z, v1.w};
      float c2[4] = {v2.x, v2.y, v2.z, v2.w};
      float c3[4] = {v3.x, v3.y, v3.z, v3.w};
      #pragma unroll
      for (int i = 0; i < 4; ++i) {
        bf16x4 bv;
        bv[0] = (bf16)c0[i]; bv[1] = (bf16)c1[i];
        bv[2] = (bf16)c2[i]; bv[3] = (bf16)c3[i];
        int row  = ng * 4 + i;
        int byte = row * 128 + kg * 8;
        byte ^= (row & 7) << 4;
        *(bf16x4*)((char*)Bs + byte) = bv;
      }
    }
    __syncthreads();
    // ---- MFMA over the two K=32 halves
    #pragma unroll
    for (int kk = 0; kk < 2; ++kk) {
      bf16x8 af[4], bfr[4];
      #pragma unroll
      for (int f = 0; f < 4; ++f) {
        int row  = wr + f * 16 + (lane & 15);
        int byte = row * 128 + kk * 64 + (lane >> 4) * 16;
        byte ^= (row & 7) << 4;
        af[f] = *(const bf16x8*)((char*)As + byte);
      }
      #pragma unroll
      for (int f = 0; f < 4; ++f) {
        int row  = wc + f * 16 + (lane & 15);
        int byte = row * 128 + kk * 64 + (lane >> 4) * 16;
        byte ^= (row & 7) << 4;
        bfr[f] = *(const bf16x8*)((char*)Bs + byte);
      }
      #pragma unroll
      for (int fm = 0; fm < 4; ++fm)
        #pragma unroll
        for (int fn = 0; fn < 4; ++fn)
          acc[fm][fn] = __builtin_amdgcn_mfma_f32_16x16x32_bf16(
              af[fm], bfr[fn], acc[fm][fn], 0, 0, 0);
    }
  }

  // ---- epilogue: bias + exact GELU -> hbuf (bf16), scatter by token
  const int g = lane >> 4, ci = lane & 15;
  #pragma unroll
  for (int fm = 0; fm < 4; ++fm) {
    #pragma unroll
    for (int rg = 0; rg < 4; ++rg) {
      int gm = m0 + wr + fm * 16 + g * 4 + rg;
      if (gm >= cnt) continue;
      size_t rowoff = (size_t)buck[gm] * HDIM;
      #pragma unroll
      for (int fn = 0; fn < 4; ++fn) {
        int nc = n0 + wc + fn * 16 + ci;
        float v = acc[fm][fn][rg] + b1[e * HDIM + nc];
        v = 0.5f * v * (1.0f + erff(v * 0.70710678118f));
        hbuf[rowoff + nc] = (bf16)v;
      }
    }
  }
}

// ---------------------------------------------------------------------------
// FFN2: y[token] = (h[token] @ W2[e] + b2[e]) * tprob[token]
// ---------------------------------------------------------------------------
__global__ __launch_bounds__(256) void ffn2_kernel(
    const bf16* __restrict__ hbuf, const float* __restrict__ W2,
    const float* __restrict__ b2, const int* __restrict__ counts,
    const int* __restrict__ bucket, const float* __restrict__ tprob,
    float* __restrict__ y)
{
  const int e   = blockIdx.z;
  const int cnt = counts[e];
  const int m0  = blockIdx.x * 128;
  if (m0 >= cnt) return;
  const int n0  = blockIdx.y * 128;

  const int tid  = threadIdx.x;
  const int lane = tid & 63;
  const int wv   = tid >> 6;
  const int wr   = (wv >> 1) * 64;
  const int wc   = (wv & 1) * 64;

  __shared__ __attribute__((aligned(16))) bf16 As[128 * 64];
  __shared__ __attribute__((aligned(16))) bf16 Bs[128 * 64];

  const int* buck = bucket + e * N_TOK;
  const float* W  = W2 + (size_t)e * HDIM * CDIM;

  f32x4 acc[4][4];
  #pragma unroll
  for (int i = 0; i < 4; ++i)
    #pragma unroll
    for (int j = 0; j < 4; ++j)
      #pragma unroll
      for (int q = 0; q < 4; ++q) acc[i][j][q] = 0.0f;

  for (int k0 = 0; k0 < HDIM; k0 += 64) {
    __syncthreads();
    // ---- stage A: h rows already bf16, 16B vector copies
    #pragma unroll
    for (int i = 0; i < 4; ++i) {
      int lin = i * 256 + tid;          // 0..1023 chunks of 8 bf16
      int row = lin >> 3;
      int c8  = lin & 7;
      int gm  = m0 + row;
      bf16x8 v;
      #pragma unroll
      for (int q = 0; q < 8; ++q) v[q] = (bf16)0.0f;
      if (gm < cnt)
        v = *(const bf16x8*)(hbuf + (size_t)buck[gm] * HDIM + k0 + c8 * 8);
      int byte = row * 128 + c8 * 16;
      byte ^= (row & 7) << 4;
      *(bf16x8*)((char*)As + byte) = v;
    }
    // ---- stage B: W2 tile [k][n] -> Bs[n][k]
    #pragma unroll
    for (int r = 0; r < 2; ++r) {
      int ng = tid & 31;
      int kg = (tid >> 5) + r * 8;
      const float* gp = W + (size_t)(k0 + kg * 4) * CDIM + n0 + ng * 4;
      float4 v0 = *(const float4*)(gp);
      float4 v1 = *(const float4*)(gp + CDIM);
      float4 v2 = *(const float4*)(gp + 2 * CDIM);
      float4 v3 = *(const float4*)(gp + 3 * CDIM);
      float c0[4] = {v0.x, v0.y, v0.z, v0.w};
      float c1[4] = {v1.x, v1.y, v1.z, v1.w};
      float c2[4] = {v2.x, v2.y, v2.z, v2.w};
      float c3[4] = {v3.x, v3.y, v3.z, v3.w};
      #pragma unroll
      for (int i = 0; i < 4; ++i) {
        bf16x4 bv;
        bv[0] = (bf16)c0[i]; bv[1] = (bf16)c1[i];
        bv[2] = (bf16)c2[i]; bv[3] = (bf16)c3[i];
        int row  = ng * 4 + i;
        int byte = row * 128 + kg * 8;
        byte ^= (row & 7) << 4;
        *(bf16x4*)((char*)Bs + byte) = bv;
      }
    }
    __syncthreads();
    #pragma unroll
    for (int kk = 0; kk < 2; ++kk) {
      bf16x8 af[4], bfr[4];
      #pragma unroll
      for (int f = 0; f < 4; ++f) {
        int row  = wr + f * 16 + (lane & 15);
        int byte = row * 128 + kk * 64 + (lane >> 4) * 16;
        byte ^= (row & 7) << 4;
        af[f] = *(const bf16x8*)((char*)As + byte);
      }
      #pragma unroll
      for (int f = 0; f < 4; ++f) {
        int row  = wc + f * 16 + (lane & 15);
        int byte = row * 128 + kk * 64 + (lane >> 4) * 16;
        byte ^= (row & 7) << 4;
        bfr[f] = *(const bf16x8*)((char*)Bs + byte);
      }
      #pragma unroll
      for (int fm = 0; fm < 4; ++fm)
        #pragma unroll
        for (int fn = 0; fn < 4; ++fn)
          acc[fm][fn] = __builtin_amdgcn_mfma_f32_16x16x32_bf16(
              af[fm], bfr[fn], acc[fm][fn], 0, 0, 0);
    }
  }

  const int g = lane >> 4, ci = lane & 15;
  #pragma unroll
  for (int fm = 0; fm < 4; ++fm) {
    #pragma unroll
    for (int rg = 0; rg < 4; ++rg) {
      int gm = m0 + wr + fm * 16 + g * 4 + rg;
      if (gm >= cnt) continue;
      int tokr = buck[gm];
      float tp = tprob[tokr];
      #pragma unroll
      for (int fn = 0; fn < 4; ++fn) {
        int nc = n0 + wc + fn * 16 + ci;
        float v = (acc[fm][fn][rg] + b2[e * CDIM + nc]) * tp;
        y[(size_t)tokr * CDIM + nc] = v;
      }
    }
  }
}

// ---------------------------------------------------------------------------
extern "C" void kernel_launch(void* const* d_in, const int* in_sizes, int n_in,
                              void* d_out, int out_size, void* d_ws, size_t ws_size,
                              hipStream_t stream)
{
  const float* x  = (const float*)d_in[0];
  const float* Wr = (const float*)d_in[1];
  const float* W1 = (const float*)d_in[2];
  const float* b1 = (const float*)d_in[3];
  const float* W2 = (const float*)d_in[4];
  const float* b2 = (const float*)d_in[5];
  float* out = (float*)d_out;

  char* ws = (char*)d_ws;
  int*   counts     = (int*)ws;                                   // 32 B
  float* importance = (float*)(ws + 32);                          // 32 B
  float* tprob      = (float*)(ws + 64);                          // 32 KB
  int*   bucket     = (int*)(ws + 64 + 4 * N_TOK);                // 256 KB
  bf16*  hbuf       = (bf16*)(ws + 64 + 4 * N_TOK + 4 * NEXP * N_TOK); // 50.3 MB

  hipMemsetAsync(ws, 0, 64, stream);   // counts + importance

  router_kernel<<<dim3(N_TOK / 128), 128, 0, stream>>>(x, Wr, tprob, bucket,
                                                       counts, importance);
  aux_kernel<<<1, 64, 0, stream>>>(counts, importance, out + (size_t)N_TOK * CDIM);
  ffn1_kernel<<<dim3(N_TOK / 128, HDIM / 128, NEXP), 256, 0, stream>>>(
      x, W1, b1, counts, bucket, hbuf);
  ffn2_kernel<<<dim3(N_TOK / 128, CDIM / 128, NEXP), 256, 0, stream>>>(
      hbuf, W2, b2, counts, bucket, tprob, out);
}

// Round 2
// 641.159 us; speedup vs baseline: 1.9631x; 1.9631x over previous
//
#include <hip/hip_runtime.h>
#include <hip/hip_bf16.h>
#include <cstdint>
#include <cmath>

#define N_TOK 8192
#define CDIM  768
#define HDIM  3072
#define NEXP  8

typedef __bf16 bf16;
typedef __bf16 bf16x4 __attribute__((ext_vector_type(4)));
typedef __bf16 bf16x8 __attribute__((ext_vector_type(8)));
typedef float  f32x4  __attribute__((ext_vector_type(4)));

__device__ __forceinline__ void load16_lds(const void* g, void* l) {
  __builtin_amdgcn_global_load_lds(
      (const __attribute__((address_space(1))) void*)g,
      (__attribute__((address_space(3))) void*)l, 16, 0, 0);
}

// ---------------------------------------------------------------------------
// Router: wave-per-token. Dot(x_row, Wr) via 64-lane partial + butterfly.
// Also converts x -> bf16 (xb) when xb != nullptr.
// ---------------------------------------------------------------------------
__global__ __launch_bounds__(256) void router2(
    const float* __restrict__ x, const float* __restrict__ Wr,
    float* __restrict__ tprob, int* __restrict__ bucket,
    int* __restrict__ counts, float* __restrict__ importance,
    bf16* __restrict__ xb)
{
  __shared__ float wr_s[CDIM * 9];
  __shared__ float imp_s[4][NEXP];

  const int tid  = threadIdx.x;
  const int lane = tid & 63;
  const int wv   = tid >> 6;
  const int tok  = blockIdx.x * 4 + wv;

  for (int idx = tid; idx < CDIM * NEXP; idx += 256)
    wr_s[(idx >> 3) * 9 + (idx & 7)] = Wr[idx];
  __syncthreads();

  float accr[NEXP];
  #pragma unroll
  for (int e2 = 0; e2 < NEXP; ++e2) accr[e2] = 0.0f;

  float4 xv[3];
  #pragma unroll
  for (int j = 0; j < 3; ++j)
    xv[j] = *(const float4*)(x + (size_t)tok * CDIM + j * 256 + lane * 4);

  if (xb) {
    #pragma unroll
    for (int j = 0; j < 3; ++j) {
      bf16x4 o;
      o[0] = (bf16)xv[j].x; o[1] = (bf16)xv[j].y;
      o[2] = (bf16)xv[j].z; o[3] = (bf16)xv[j].w;
      *(bf16x4*)(xb + (size_t)tok * CDIM + j * 256 + lane * 4) = o;
    }
  }

  #pragma unroll
  for (int j = 0; j < 3; ++j) {
    const float xq[4] = {xv[j].x, xv[j].y, xv[j].z, xv[j].w};
    #pragma unroll
    for (int q = 0; q < 4; ++q) {
      const int c = j * 256 + lane * 4 + q;
      const float* wrow = &wr_s[c * 9];
      #pragma unroll
      for (int e2 = 0; e2 < NEXP; ++e2)
        accr[e2] = fmaf(xq[q], wrow[e2], accr[e2]);
    }
  }

  #pragma unroll
  for (int e2 = 0; e2 < NEXP; ++e2) {
    float v = accr[e2];
    v += __shfl_xor(v, 1);  v += __shfl_xor(v, 2);  v += __shfl_xor(v, 4);
    v += __shfl_xor(v, 8);  v += __shfl_xor(v, 16); v += __shfl_xor(v, 32);
    accr[e2] = v;
  }

  // softmax + argmax (strict > keeps FIRST max, matching jnp.argmax)
  float m = accr[0]; int be = 0;
  #pragma unroll
  for (int e2 = 1; e2 < NEXP; ++e2) if (accr[e2] > m) { m = accr[e2]; be = e2; }
  float pr[NEXP]; float s = 0.0f;
  #pragma unroll
  for (int e2 = 0; e2 < NEXP; ++e2) { pr[e2] = expf(accr[e2] - m); s += pr[e2]; }
  const float inv = 1.0f / s;

  if (lane == 0) {
    tprob[tok] = pr[be] * inv;
    int rank = atomicAdd(&counts[be], 1);
    bucket[be * N_TOK + rank] = tok;
    #pragma unroll
    for (int e2 = 0; e2 < NEXP; ++e2) imp_s[wv][e2] = pr[e2] * inv;
  }
  __syncthreads();
  if (tid < NEXP)
    atomicAdd(&importance[tid],
              imp_s[0][tid] + imp_s[1][tid] + imp_s[2][tid] + imp_s[3][tid]);
}

// ---------------------------------------------------------------------------
__global__ void aux_kernel(const int* __restrict__ counts,
                           const float* __restrict__ importance,
                           float* __restrict__ out_aux)
{
  if (threadIdx.x == 0) {
    float s = 0.0f;
    for (int e2 = 0; e2 < NEXP; ++e2) s += importance[e2] * (float)counts[e2];
    out_aux[0] = (float)NEXP * s / ((float)N_TOK * (float)N_TOK);
  }
}

// ---------------------------------------------------------------------------
// W [E][R][S] fp32  ->  WT [E][S][R] bf16   (LDS-tiled 64x64 transpose)
// ---------------------------------------------------------------------------
__global__ __launch_bounds__(256) void transpose_w(
    const float* __restrict__ W, bf16* __restrict__ WT, int R, int S)
{
  __shared__ float t[64][65];
  const int r0 = blockIdx.x * 64, s0 = blockIdx.y * 64, e = blockIdx.z;
  const float* We = W + (size_t)e * R * S;
  bf16* WTe = WT + (size_t)e * R * S;
  const int tid = threadIdx.x;
  const int lr = tid >> 4, lc4 = tid & 15;

  #pragma unroll
  for (int j = 0; j < 4; ++j) {
    int r = lr + j * 16;
    float4 v = *(const float4*)(We + (size_t)(r0 + r) * S + s0 + lc4 * 4);
    t[r][lc4 * 4 + 0] = v.x; t[r][lc4 * 4 + 1] = v.y;
    t[r][lc4 * 4 + 2] = v.z; t[r][lc4 * 4 + 3] = v.w;
  }
  __syncthreads();
  #pragma unroll
  for (int j = 0; j < 4; ++j) {
    int sI = lr + j * 16;
    bf16x4 o;
    #pragma unroll
    for (int q = 0; q < 4; ++q) o[q] = (bf16)t[lc4 * 4 + q][sI];
    *(bf16x4*)(WTe + (size_t)(s0 + sI) * R + r0 + lc4 * 4) = o;
  }
}

// ---------------------------------------------------------------------------
// Grouped GEMM, m97 structure: BM=128, BK=64, 4 waves, global_load_lds w=16
// with pre-swizzled source columns; XOR-swizzled ds_read_b128.
// A = gathered token rows (bf16 [N_TOK][KDIM]); B = WT [E][NTOT][KDIM].
// ---------------------------------------------------------------------------
template<int BN, int KDIM, bool GELU>
__global__ __launch_bounds__(256) void ffn_kernel(
    const bf16* __restrict__ Abuf, const bf16* __restrict__ WT,
    const float* __restrict__ bias, const int* __restrict__ counts,
    const int* __restrict__ bucket, const float* __restrict__ tprob,
    bf16* __restrict__ out_bf, float* __restrict__ out_f)
{
  constexpr int WGN  = BN / 64;       // waves along N
  constexpr int WGM  = 4 / WGN;       // waves along M
  constexpr int WM   = 128 / WGM;     // per-wave M
  constexpr int FM   = WM / 16;
  constexpr int FN   = 4;             // per-wave N = 64
  constexpr int NBI  = BN / 32;       // B-stage instrs per wave
  constexpr int NTOT = GELU ? HDIM : CDIM;

  const int e   = blockIdx.z;
  const int cnt = counts[e];
  const int m0  = blockIdx.x * 128;
  if (m0 >= cnt) return;
  const int n0  = blockIdx.y * BN;

  const int tid  = threadIdx.x;
  const int lane = tid & 63;
  const int wv   = tid >> 6;
  const int wr   = (wv / WGN) * WM;
  const int wc   = (wv % WGN) * 64;

  __shared__ __attribute__((aligned(1024))) bf16 As[128 * 64];
  __shared__ __attribute__((aligned(1024))) bf16 Bs[BN * 64];

  const int* buck = bucket + e * N_TOK;
  const bf16* WTe = WT + (size_t)e * NTOT * KDIM;

  const int c16 = (lane & 7) * 16;    // byte column of this lane within a row

  const char* srcA[4];
  char* dstA[4];
  #pragma unroll
  for (int i = 0; i < 4; ++i) {
    int row = wv * 32 + i * 8 + (lane >> 3);
    int gm  = m0 + row;
    int tk  = (gm < cnt) ? buck[gm] : buck[m0];
    srcA[i] = (const char*)(Abuf + (size_t)tk * KDIM) + (c16 ^ ((row & 7) << 4));
    dstA[i] = (char*)As + (wv * 32 + i * 8) * 128;
  }
  const char* srcB[NBI];
  char* dstB[NBI];
  #pragma unroll
  for (int i = 0; i < NBI; ++i) {
    int row = wv * (BN / 4) + i * 8 + (lane >> 3);
    srcB[i] = (const char*)(WTe + (size_t)(n0 + row) * KDIM) + (c16 ^ ((row & 7) << 4));
    dstB[i] = (char*)Bs + (wv * (BN / 4) + i * 8) * 128;
  }

  f32x4 acc[FM][FN];
  #pragma unroll
  for (int i = 0; i < FM; ++i)
    #pragma unroll
    for (int j = 0; j < FN; ++j)
      #pragma unroll
      for (int q = 0; q < 4; ++q) acc[i][j][q] = 0.0f;

  for (int k0 = 0; k0 < KDIM; k0 += 64) {
    __syncthreads();
    #pragma unroll
    for (int i = 0; i < 4; ++i) { load16_lds(srcA[i], dstA[i]); srcA[i] += 128; }
    #pragma unroll
    for (int i = 0; i < NBI; ++i) { load16_lds(srcB[i], dstB[i]); srcB[i] += 128; }
    __syncthreads();   // compiler inserts vmcnt(0) drain here

    #pragma unroll
    for (int kk = 0; kk < 2; ++kk) {
      bf16x8 af[FM], bfr[FN];
      #pragma unroll
      for (int f = 0; f < FM; ++f) {
        int row  = wr + f * 16 + (lane & 15);
        int byte = row * 128 + kk * 64 + (lane >> 4) * 16;
        byte ^= (row & 7) << 4;
        af[f] = *(const bf16x8*)((char*)As + byte);
      }
      #pragma unroll
      for (int f = 0; f < FN; ++f) {
        int row  = wc + f * 16 + (lane & 15);
        int byte = row * 128 + kk * 64 + (lane >> 4) * 16;
        byte ^= (row & 7) << 4;
        bfr[f] = *(const bf16x8*)((char*)Bs + byte);
      }
      #pragma unroll
      for (int fm = 0; fm < FM; ++fm)
        #pragma unroll
        for (int fn = 0; fn < FN; ++fn)
          acc[fm][fn] = __builtin_amdgcn_mfma_f32_16x16x32_bf16(
              af[fm], bfr[fn], acc[fm][fn], 0, 0, 0);
    }
  }

  const int g = lane >> 4, ci = lane & 15;
  #pragma unroll
  for (int fm = 0; fm < FM; ++fm) {
    #pragma unroll
    for (int rg = 0; rg < 4; ++rg) {
      int gm = m0 + wr + fm * 16 + g * 4 + rg;
      if (gm >= cnt) continue;
      int tokr = buck[gm];
      if (GELU) {
        size_t ro = (size_t)tokr * HDIM;
        #pragma unroll
        for (int fn = 0; fn < FN; ++fn) {
          int nc = n0 + wc + fn * 16 + ci;
          float v = acc[fm][fn][rg] + bias[e * NTOT + nc];
          v = 0.5f * v * (1.0f + erff(v * 0.70710678118f));
          out_bf[ro + nc] = (bf16)v;
        }
      } else {
        float tp = tprob[tokr];
        size_t ro = (size_t)tokr * CDIM;
        #pragma unroll
        for (int fn = 0; fn < FN; ++fn) {
          int nc = n0 + wc + fn * 16 + ci;
          out_f[ro + nc] = (acc[fm][fn][rg] + bias[e * NTOT + nc]) * tp;
        }
      }
    }
  }
}

// ---------------------------------------------------------------------------
// Fallback FFN kernels (round-1, verified) for small workspaces.
// ---------------------------------------------------------------------------
__global__ __launch_bounds__(256) void ffn1_fb(
    const float* __restrict__ x, const float* __restrict__ W1,
    const float* __restrict__ b1, const int* __restrict__ counts,
    const int* __restrict__ bucket, bf16* __restrict__ hbuf)
{
  const int e   = blockIdx.z;
  const int cnt = counts[e];
  const int m0  = blockIdx.x * 128;
  if (m0 >= cnt) return;
  const int n0  = blockIdx.y * 128;
  const int tid  = threadIdx.x;
  const int lane = tid & 63;
  const int wv   = tid >> 6;
  const int wr   = (wv >> 1) * 64;
  const int wc   = (wv & 1) * 64;
  __shared__ __attribute__((aligned(16))) bf16 As[128 * 64];
  __shared__ __attribute__((aligned(16))) bf16 Bs[128 * 64];
  const int* buck = bucket + e * N_TOK;
  const float* W  = W1 + (size_t)e * CDIM * HDIM;
  f32x4 acc[4][4];
  #pragma unroll
  for (int i = 0; i < 4; ++i)
    #pragma unroll
    for (int j = 0; j < 4; ++j)
      #pragma unroll
      for (int q = 0; q < 4; ++q) acc[i][j][q] = 0.0f;
  for (int k0 = 0; k0 < CDIM; k0 += 64) {
    __syncthreads();
    #pragma unroll
    for (int i = 0; i < 8; ++i) {
      int lin = i * 256 + tid;
      int row = lin >> 4, c4 = lin & 15, gm = m0 + row;
      float4 v = make_float4(0.f, 0.f, 0.f, 0.f);
      if (gm < cnt) v = *(const float4*)(x + (size_t)buck[gm] * CDIM + k0 + c4 * 4);
      bf16x4 bv; bv[0] = (bf16)v.x; bv[1] = (bf16)v.y; bv[2] = (bf16)v.z; bv[3] = (bf16)v.w;
      int byte = row * 128 + c4 * 8; byte ^= (row & 7) << 4;
      *(bf16x4*)((char*)As + byte) = bv;
    }
    #pragma unroll
    for (int r = 0; r < 2; ++r) {
      int ng = tid & 31, kg = (tid >> 5) + r * 8;
      const float* gp = W + (size_t)(k0 + kg * 4) * HDIM + n0 + ng * 4;
      float4 v0 = *(const float4*)(gp);
      float4 v1 = *(const float4*)(gp + HDIM);
      float4 v2 = *(const float4*)(gp + 2 * HDIM);
      float4 v3 = *(const float4*)(gp + 3 * HDIM);
      float c0[4] = {v0.x, v0.y, v0.z, v0.w};
      float c1[4] = {v1.x, v1.y, v1.z, v1.w};
      float c2[4] = {v2.x, v2.y, v2.z, v2.w};
      float c3[4] = {v3.x, v3.y, v3.z, v3.w};
      #pragma unroll
      for (int i = 0; i < 4; ++i) {
        bf16x4 bv; bv[0] = (bf16)c0[i]; bv[1] = (bf16)c1[i]; bv[2] = (bf16)c2[i]; bv[3] = (bf16)c3[i];
        int row = ng * 4 + i;
        int byte = row * 128 + kg * 8; byte ^= (row & 7) << 4;
        *(bf16x4*)((char*)Bs + byte) = bv;
      }
    }
    __syncthreads();
    #pragma unroll
    for (int kk = 0; kk < 2; ++kk) {
      bf16x8 af[4], bfr[4];
      #pragma unroll
      for (int f = 0; f < 4; ++f) {
        int row = wr + f * 16 + (lane & 15);
        int byte = row * 128 + kk * 64 + (lane >> 4) * 16; byte ^= (row & 7) << 4;
        af[f] = *(const bf16x8*)((char*)As + byte);
      }
      #pragma unroll
      for (int f = 0; f < 4; ++f) {
        int row = wc + f * 16 + (lane & 15);
        int byte = row * 128 + kk * 64 + (lane >> 4) * 16; byte ^= (row & 7) << 4;
        bfr[f] = *(const bf16x8*)((char*)Bs + byte);
      }
      #pragma unroll
      for (int fm = 0; fm < 4; ++fm)
        #pragma unroll
        for (int fn = 0; fn < 4; ++fn)
          acc[fm][fn] = __builtin_amdgcn_mfma_f32_16x16x32_bf16(af[fm], bfr[fn], acc[fm][fn], 0, 0, 0);
    }
  }
  const int g = lane >> 4, ci = lane & 15;
  #pragma unroll
  for (int fm = 0; fm < 4; ++fm)
    #pragma unroll
    for (int rg = 0; rg < 4; ++rg) {
      int gm = m0 + wr + fm * 16 + g * 4 + rg;
      if (gm >= cnt) continue;
      size_t ro = (size_t)buck[gm] * HDIM;
      #pragma unroll
      for (int fn = 0; fn < 4; ++fn) {
        int nc = n0 + wc + fn * 16 + ci;
        float v = acc[fm][fn][rg] + b1[e * HDIM + nc];
        v = 0.5f * v * (1.0f + erff(v * 0.70710678118f));
        hbuf[ro + nc] = (bf16)v;
      }
    }
}

__global__ __launch_bounds__(256) void ffn2_fb(
    const bf16* __restrict__ hbuf, const float* __restrict__ W2,
    const float* __restrict__ b2, const int* __restrict__ counts,
    const int* __restrict__ bucket, const float* __restrict__ tprob,
    float* __restrict__ y)
{
  const int e   = blockIdx.z;
  const int cnt = counts[e];
  const int m0  = blockIdx.x * 128;
  if (m0 >= cnt) return;
  const int n0  = blockIdx.y * 128;
  const int tid  = threadIdx.x;
  const int lane = tid & 63;
  const int wv   = tid >> 6;
  const int wr   = (wv >> 1) * 64;
  const int wc   = (wv & 1) * 64;
  __shared__ __attribute__((aligned(16))) bf16 As[128 * 64];
  __shared__ __attribute__((aligned(16))) bf16 Bs[128 * 64];
  const int* buck = bucket + e * N_TOK;
  const float* W  = W2 + (size_t)e * HDIM * CDIM;
  f32x4 acc[4][4];
  #pragma unroll
  for (int i = 0; i < 4; ++i)
    #pragma unroll
    for (int j = 0; j < 4; ++j)
      #pragma unroll
      for (int q = 0; q < 4; ++q) acc[i][j][q] = 0.0f;
  for (int k0 = 0; k0 < HDIM; k0 += 64) {
    __syncthreads();
    #pragma unroll
    for (int i = 0; i < 4; ++i) {
      int lin = i * 256 + tid;
      int row = lin >> 3, c8 = lin & 7, gm = m0 + row;
      bf16x8 v;
      #pragma unroll
      for (int q = 0; q < 8; ++q) v[q] = (bf16)0.0f;
      if (gm < cnt) v = *(const bf16x8*)(hbuf + (size_t)buck[gm] * HDIM + k0 + c8 * 8);
      int byte = row * 128 + c8 * 16; byte ^= (row & 7) << 4;
      *(bf16x8*)((char*)As + byte) = v;
    }
    #pragma unroll
    for (int r = 0; r < 2; ++r) {
      int ng = tid & 31, kg = (tid >> 5) + r * 8;
      const float* gp = W + (size_t)(k0 + kg * 4) * CDIM + n0 + ng * 4;
      float4 v0 = *(const float4*)(gp);
      float4 v1 = *(const float4*)(gp + CDIM);
      float4 v2 = *(const float4*)(gp + 2 * CDIM);
      float4 v3 = *(const float4*)(gp + 3 * CDIM);
      float c0[4] = {v0.x, v0.y, v0.z, v0.w};
      float c1[4] = {v1.x, v1.y, v1.z, v1.w};
      float c2[4] = {v2.x, v2.y, v2.z, v2.w};
      float c3[4] = {v3.x, v3.y, v3.z, v3.w};
      #pragma unroll
      for (int i = 0; i < 4; ++i) {
        bf16x4 bv; bv[0] = (bf16)c0[i]; bv[1] = (bf16)c1[i]; bv[2] = (bf16)c2[i]; bv[3] = (bf16)c3[i];
        int row = ng * 4 + i;
        int byte = row * 128 + kg * 8; byte ^= (row & 7) << 4;
        *(bf16x4*)((char*)Bs + byte) = bv;
      }
    }
    __syncthreads();
    #pragma unroll
    for (int kk = 0; kk < 2; ++kk) {
      bf16x8 af[4], bfr[4];
      #pragma unroll
      for (int f = 0; f < 4; ++f) {
        int row = wr + f * 16 + (lane & 15);
        int byte = row * 128 + kk * 64 + (lane >> 4) * 16; byte ^= (row & 7) << 4;
        af[f] = *(const bf16x8*)((char*)As + byte);
      }
      #pragma unroll
      for (int f = 0; f < 4; ++f) {
        int row = wc + f * 16 + (lane & 15);
        int byte = row * 128 + kk * 64 + (lane >> 4) * 16; byte ^= (row & 7) << 4;
        bfr[f] = *(const bf16x8*)((char*)Bs + byte);
      }
      #pragma unroll
      for (int fm = 0; fm < 4; ++fm)
        #pragma unroll
        for (int fn = 0; fn < 4; ++fn)
          acc[fm][fn] = __builtin_amdgcn_mfma_f32_16x16x32_bf16(af[fm], bfr[fn], acc[fm][fn], 0, 0, 0);
    }
  }
  const int g = lane >> 4, ci = lane & 15;
  #pragma unroll
  for (int fm = 0; fm < 4; ++fm)
    #pragma unroll
    for (int rg = 0; rg < 4; ++rg) {
      int gm = m0 + wr + fm * 16 + g * 4 + rg;
      if (gm >= cnt) continue;
      int tokr = buck[gm];
      float tp = tprob[tokr];
      #pragma unroll
      for (int fn = 0; fn < 4; ++fn) {
        int nc = n0 + wc + fn * 16 + ci;
        y[(size_t)tokr * CDIM + nc] = (acc[fm][fn][rg] + b2[e * CDIM + nc]) * tp;
      }
    }
}

// ---------------------------------------------------------------------------
extern "C" void kernel_launch(void* const* d_in, const int* in_sizes, int n_in,
                              void* d_out, int out_size, void* d_ws, size_t ws_size,
                              hipStream_t stream)
{
  const float* x  = (const float*)d_in[0];
  const float* Wr = (const float*)d_in[1];
  const float* W1 = (const float*)d_in[2];
  const float* b1 = (const float*)d_in[3];
  const float* W2 = (const float*)d_in[4];
  const float* b2 = (const float*)d_in[5];
  float* out = (float*)d_out;

  char* ws = (char*)d_ws;
  int*   counts     = (int*)ws;                    // 32 B
  float* importance = (float*)(ws + 64);           // 32 B
  float* tprob      = (float*)(ws + 1024);         // 32 KB
  int*   bucket     = (int*)(ws + 65536);          // 256 KB -> ends 327680

  const size_t NEED_BIG = 138739712ull;
  const bool big = ws_size >= NEED_BIG;

  hipMemsetAsync(ws, 0, 128, stream);   // counts + importance

  if (big) {
    bf16* xb   = (bf16*)(ws + 327680);             // 12.58 MB
    bf16* hbuf = (bf16*)(ws + 12910592);           // 50.33 MB
    bf16* w1t  = (bf16*)(ws + 63242240);           // 37.75 MB  [E][H][C]
    bf16* w2t  = (bf16*)(ws + 100990976);          // 37.75 MB  [E][C][H]

    router2<<<dim3(N_TOK / 4), 256, 0, stream>>>(x, Wr, tprob, bucket,
                                                 counts, importance, xb);
    aux_kernel<<<1, 64, 0, stream>>>(counts, importance,
                                     out + (size_t)N_TOK * CDIM);
    transpose_w<<<dim3(CDIM / 64, HDIM / 64, NEXP), 256, 0, stream>>>(
        W1, w1t, CDIM, HDIM);
    transpose_w<<<dim3(HDIM / 64, CDIM / 64, NEXP), 256, 0, stream>>>(
        W2, w2t, HDIM, CDIM);
    ffn_kernel<128, CDIM, true><<<dim3(N_TOK / 128, HDIM / 128, NEXP), 256, 0, stream>>>(
        xb, w1t, b1, counts, bucket, nullptr, hbuf, nullptr);
    ffn_kernel<64, HDIM, false><<<dim3(N_TOK / 128, CDIM / 64, NEXP), 256, 0, stream>>>(
        hbuf, w2t, b2, counts, bucket, tprob, nullptr, out);
  } else {
    bf16* hbuf = (bf16*)(ws + 327680);             // 50.33 MB (fallback layout)
    router2<<<dim3(N_TOK / 4), 256, 0, stream>>>(x, Wr, tprob, bucket,
                                                 counts, importance, nullptr);
    aux_kernel<<<1, 64, 0, stream>>>(counts, importance,
                                     out + (size_t)N_TOK * CDIM);
    ffn1_fb<<<dim3(N_TOK / 128, HDIM / 128, NEXP), 256, 0, stream>>>(
        x, W1, b1, counts, bucket, hbuf);
    ffn2_fb<<<dim3(N_TOK / 128, CDIM / 128, NEXP), 256, 0, stream>>>(
        hbuf, W2, b2, counts, bucket, tprob, out);
  }
}

// Round 3
// 312.172 us; speedup vs baseline: 4.0320x; 2.0539x over previous
//
#include <hip/hip_runtime.h>
#include <hip/hip_bf16.h>
#include <cstdint>
#include <cmath>

#define N_TOK 8192
#define CDIM  768
#define HDIM  3072
#define NEXP  8

typedef __bf16 bf16;
typedef __bf16 bf16x4 __attribute__((ext_vector_type(4)));
typedef __bf16 bf16x8 __attribute__((ext_vector_type(8)));
typedef float  f32x4  __attribute__((ext_vector_type(4)));

// ws byte offsets
#define WS_COUNTS 0          // 8 ints
#define WS_IMP    64         // 8 floats
#define WS_OFF    128        // 9 ints (off[8] = padded total)
#define WS_TPROB  1024       // 8192 f32
#define WS_BUCKET 65536      // 8*8192 ints
#define WS_TOKMAP 327680     // 9216 ints
#define WS_TPG    364544     // 9216 f32
#define WS_XGT    (1u<<20)   // 72*12*16384 = 14,155,776
#define WS_W1T    (16u<<20)  // 8*48*12*8192 = 37,748,736
#define WS_HBUF   (56u<<20)  // 72*48*16384 = 56,623,104 -> ends 115,343,360
#define WS_W2T    (1u<<20)   // overlaps XGT+W1T, written after ffn1 (37.75 MB)

__device__ __forceinline__ void load16_lds(const void* g, void* l) {
  __builtin_amdgcn_global_load_lds(
      (const __attribute__((address_space(1))) void*)g,
      (__attribute__((address_space(3))) void*)l, 16, 0, 0);
}

// ---------------------------------------------------------------------------
// Router: wave-per-token dot(x,Wr) + softmax + argmax + bucket + importance.
// ---------------------------------------------------------------------------
__global__ __launch_bounds__(256) void router2(
    const float* __restrict__ x, const float* __restrict__ Wr,
    float* __restrict__ tprob, int* __restrict__ bucket,
    int* __restrict__ counts, float* __restrict__ importance)
{
  __shared__ float wr_s[CDIM * 9];
  __shared__ float imp_s[4][NEXP];

  const int tid  = threadIdx.x;
  const int lane = tid & 63;
  const int wv   = tid >> 6;
  const int tok  = blockIdx.x * 4 + wv;

  for (int idx = tid; idx < CDIM * NEXP; idx += 256)
    wr_s[(idx >> 3) * 9 + (idx & 7)] = Wr[idx];
  __syncthreads();

  float accr[NEXP];
  #pragma unroll
  for (int e2 = 0; e2 < NEXP; ++e2) accr[e2] = 0.0f;

  float4 xv[3];
  #pragma unroll
  for (int j = 0; j < 3; ++j)
    xv[j] = *(const float4*)(x + (size_t)tok * CDIM + j * 256 + lane * 4);

  #pragma unroll
  for (int j = 0; j < 3; ++j) {
    const float xq[4] = {xv[j].x, xv[j].y, xv[j].z, xv[j].w};
    #pragma unroll
    for (int q = 0; q < 4; ++q) {
      const int c = j * 256 + lane * 4 + q;
      const float* wrow = &wr_s[c * 9];
      #pragma unroll
      for (int e2 = 0; e2 < NEXP; ++e2)
        accr[e2] = fmaf(xq[q], wrow[e2], accr[e2]);
    }
  }

  #pragma unroll
  for (int e2 = 0; e2 < NEXP; ++e2) {
    float v = accr[e2];
    v += __shfl_xor(v, 1);  v += __shfl_xor(v, 2);  v += __shfl_xor(v, 4);
    v += __shfl_xor(v, 8);  v += __shfl_xor(v, 16); v += __shfl_xor(v, 32);
    accr[e2] = v;
  }

  float m = accr[0]; int be = 0;
  #pragma unroll
  for (int e2 = 1; e2 < NEXP; ++e2) if (accr[e2] > m) { m = accr[e2]; be = e2; }
  float pr[NEXP]; float s = 0.0f;
  #pragma unroll
  for (int e2 = 0; e2 < NEXP; ++e2) { pr[e2] = expf(accr[e2] - m); s += pr[e2]; }
  const float inv = 1.0f / s;

  if (lane == 0) {
    tprob[tok] = pr[be] * inv;
    int rank = atomicAdd(&counts[be], 1);
    bucket[be * N_TOK + rank] = tok;
    #pragma unroll
    for (int e2 = 0; e2 < NEXP; ++e2) imp_s[wv][e2] = pr[e2] * inv;
  }
  __syncthreads();
  if (tid < NEXP)
    atomicAdd(&importance[tid],
              imp_s[0][tid] + imp_s[1][tid] + imp_s[2][tid] + imp_s[3][tid]);
}

// ---------------------------------------------------------------------------
// aux loss + 128-aligned expert offsets.
// ---------------------------------------------------------------------------
__global__ void aux_kernel(const int* __restrict__ counts,
                           const float* __restrict__ importance,
                           float* __restrict__ out_aux, int* __restrict__ off)
{
  if (threadIdx.x == 0) {
    float s = 0.0f; int o = 0;
    off[0] = 0;
    for (int e2 = 0; e2 < NEXP; ++e2) {
      s += importance[e2] * (float)counts[e2];
      o += (counts[e2] + 127) & ~127;
      off[e2 + 1] = o;
    }
    out_aux[0] = (float)NEXP * s / ((float)N_TOK * (float)N_TOK);
  }
}

// ---------------------------------------------------------------------------
// Gather: pack routed token rows into xgT [tile][kc:12][128][64] bf16,
// XOR-swizzled within each 128B row. Pads zeroed. tokmap/tpg per slot.
// ---------------------------------------------------------------------------
__global__ __launch_bounds__(256) void gather_kernel(
    const float* __restrict__ x, const float* __restrict__ tprob,
    const int* __restrict__ bucket, const int* __restrict__ counts,
    const int* __restrict__ off, bf16* __restrict__ xgT,
    int* __restrict__ tokmap, float* __restrict__ tpg)
{
  const int tid = threadIdx.x, lane = tid & 63, wv = tid >> 6;
  const int s = blockIdx.x * 4 + wv;
  const int ptot = off[8];
  if (s >= ptot) return;
  int e = 0;
  #pragma unroll
  for (int q = 0; q < 7; ++q) if (s >= off[q + 1]) e = q + 1;
  const int rank = s - off[e];
  const bool valid = rank < counts[e];
  const int token = valid ? bucket[e * N_TOK + rank] : -1;
  if (lane == 0) { tokmap[s] = token; tpg[s] = valid ? tprob[token] : 0.0f; }
  const int tile = s >> 7, r = s & 127;
  #pragma unroll
  for (int j = 0; j < 3; ++j) {
    const int col = j * 256 + lane * 4;
    const int kc = col >> 6, cw = col & 63;
    bf16x4 o;
    if (valid) {
      float4 v = *(const float4*)(x + (size_t)token * CDIM + col);
      o[0] = (bf16)v.x; o[1] = (bf16)v.y; o[2] = (bf16)v.z; o[3] = (bf16)v.w;
    } else {
      o[0] = o[1] = o[2] = o[3] = (bf16)0.0f;
    }
    char* dst = (char*)xgT + (((size_t)tile * 12 + kc) * 128 + r) * 128
                + ((cw * 2) ^ ((r & 7) << 4));
    *(bf16x4*)dst = o;
  }
}

// ---------------------------------------------------------------------------
// W [E][R][S] fp32 -> tiled bf16 [E][S/64][R/64][64 rows][64 cols], swizzled.
// ---------------------------------------------------------------------------
__global__ __launch_bounds__(256) void transpose_w(
    const float* __restrict__ W, bf16* __restrict__ WT, int R, int S)
{
  __shared__ float t[64][65];
  const int r0 = blockIdx.x * 64, s0 = blockIdx.y * 64, e = blockIdx.z;
  const float* We = W + (size_t)e * R * S;
  const int NT = S >> 6, NK = R >> 6;
  char* outT = (char*)WT + (((size_t)e * NT + (s0 >> 6)) * NK + (r0 >> 6)) * 8192;
  const int tid = threadIdx.x, lr = tid >> 4, lc4 = tid & 15;

  #pragma unroll
  for (int j = 0; j < 4; ++j) {
    int r = lr + j * 16;
    float4 v = *(const float4*)(We + (size_t)(r0 + r) * S + s0 + lc4 * 4);
    t[r][lc4 * 4 + 0] = v.x; t[r][lc4 * 4 + 1] = v.y;
    t[r][lc4 * 4 + 2] = v.z; t[r][lc4 * 4 + 3] = v.w;
  }
  __syncthreads();
  #pragma unroll
  for (int j = 0; j < 4; ++j) {
    int sI = lr + j * 16;
    bf16x4 o;
    #pragma unroll
    for (int q = 0; q < 4; ++q) o[q] = (bf16)t[lc4 * 4 + q][sI];
    *(bf16x4*)(outT + sI * 128 + ((lc4 * 8) ^ ((sI & 7) << 4))) = o;
  }
}

// ---------------------------------------------------------------------------
// FFN1: h = gelu(xg @ W1 + b1). BM=128 BN=64 BK=64, dbuf LDS, 4 waves.
// All stage loads are contiguous 1KB DMAs (pre-tiled, pre-swizzled inputs).
// ---------------------------------------------------------------------------
__global__ __launch_bounds__(256) void ffn1_v3(
    const bf16* __restrict__ xgT, const bf16* __restrict__ w1tT,
    const float* __restrict__ b1, const int* __restrict__ off,
    bf16* __restrict__ hbufT)
{
  const int ptot = off[8];
  const int m0 = blockIdx.x * 128;
  if (m0 >= ptot) return;
  int e = 0;
  #pragma unroll
  for (int q = 0; q < 7; ++q) if (m0 >= off[q + 1]) e = q + 1;
  const int n0 = blockIdx.y * 64;

  const int tid = threadIdx.x, lane = tid & 63, wv = tid >> 6;
  const int wr = wv * 32;

  __shared__ __attribute__((aligned(1024))) char smem[49152];
  // A0 @0 (16K), A1 @16K, B0 @32K (8K), B1 @40K

  const char* aBase = (const char*)xgT + (size_t)blockIdx.x * 12 * 16384;
  const char* bBase = (const char*)w1tT + (((size_t)e * 48 + blockIdx.y) * 12) * 8192;

  f32x4 acc[2][4];
  #pragma unroll
  for (int i = 0; i < 2; ++i)
    #pragma unroll
    for (int j = 0; j < 4; ++j)
      #pragma unroll
      for (int q = 0; q < 4; ++q) acc[i][j][q] = 0.0f;

  // prologue stage kc=0 into buf 0
  {
    const char* aS = aBase + (size_t)wv * 4096 + lane * 16;
    char* aD = smem + wv * 4096;
    const char* bS = bBase + (size_t)wv * 2048 + lane * 16;
    char* bD = smem + 32768 + wv * 2048;
    #pragma unroll
    for (int i = 0; i < 4; ++i) load16_lds(aS + i * 1024, aD + i * 1024);
    #pragma unroll
    for (int i = 0; i < 2; ++i) load16_lds(bS + i * 1024, bD + i * 1024);
  }
  __syncthreads();

  for (int kc = 0; kc < 12; ++kc) {
    const int cur = kc & 1;
    if (kc + 1 < 12) {
      const int nb = cur ^ 1;
      const char* aS = aBase + (size_t)(kc + 1) * 16384 + wv * 4096 + lane * 16;
      char* aD = smem + nb * 16384 + wv * 4096;
      const char* bS = bBase + (size_t)(kc + 1) * 8192 + wv * 2048 + lane * 16;
      char* bD = smem + 32768 + nb * 8192 + wv * 2048;
      #pragma unroll
      for (int i = 0; i < 4; ++i) load16_lds(aS + i * 1024, aD + i * 1024);
      #pragma unroll
      for (int i = 0; i < 2; ++i) load16_lds(bS + i * 1024, bD + i * 1024);
    }
    const char* A = smem + cur * 16384;
    const char* B = smem + 32768 + cur * 8192;
    #pragma unroll
    for (int kk = 0; kk < 2; ++kk) {
      bf16x8 af[2], bfr[4];
      #pragma unroll
      for (int f = 0; f < 2; ++f) {
        int row = wr + f * 16 + (lane & 15);
        int byte = row * 128 + kk * 64 + (lane >> 4) * 16;
        byte ^= (row & 7) << 4;
        af[f] = *(const bf16x8*)(A + byte);
      }
      #pragma unroll
      for (int f = 0; f < 4; ++f) {
        int row = f * 16 + (lane & 15);
        int byte = row * 128 + kk * 64 + (lane >> 4) * 16;
        byte ^= (row & 7) << 4;
        bfr[f] = *(const bf16x8*)(B + byte);
      }
      #pragma unroll
      for (int fm = 0; fm < 2; ++fm)
        #pragma unroll
        for (int fn = 0; fn < 4; ++fn)
          acc[fm][fn] = __builtin_amdgcn_mfma_f32_16x16x32_bf16(
              af[fm], bfr[fn], acc[fm][fn], 0, 0, 0);
    }
    __syncthreads();
  }

  // epilogue: bias + tanh-GELU -> swizzled bf16 C tile in LDS -> linear copy
  const int g = lane >> 4, ci = lane & 15;
  float b1v[4];
  #pragma unroll
  for (int fn = 0; fn < 4; ++fn) b1v[fn] = b1[e * HDIM + n0 + fn * 16 + ci];

  #pragma unroll
  for (int fm = 0; fm < 2; ++fm)
    #pragma unroll
    for (int fn = 0; fn < 4; ++fn)
      #pragma unroll
      for (int rg = 0; rg < 4; ++rg) {
        int row = wr + fm * 16 + g * 4 + rg;
        float v = acc[fm][fn][rg] + b1v[fn];
        float t3 = v + 0.044715f * v * v * v;
        float gel = v / (1.0f + __expf(-1.5957691216f * t3));
        int col = fn * 16 + ci;
        int byte = row * 128 + ((col * 2) ^ ((row & 7) << 4));
        *(bf16*)(smem + byte) = (bf16)gel;
      }
  __syncthreads();

  char* hdst = (char*)hbufT + ((size_t)blockIdx.x * 48 + blockIdx.y) * 16384;
  #pragma unroll
  for (int i = 0; i < 4; ++i) {
    int b = (i * 256 + tid) * 16;
    *(f32x4*)(hdst + b) = *(const f32x4*)(smem + b);
  }
}

// ---------------------------------------------------------------------------
// FFN2: y[tok] = (h @ W2 + b2) * tprob. Same structure, NKC=48, scatter out.
// ---------------------------------------------------------------------------
__global__ __launch_bounds__(256) void ffn2_v3(
    const bf16* __restrict__ hbufT, const bf16* __restrict__ w2tT,
    const float* __restrict__ b2, const int* __restrict__ off,
    const int* __restrict__ tokmap, const float* __restrict__ tpg,
    float* __restrict__ y)
{
  const int ptot = off[8];
  const int m0 = blockIdx.x * 128;
  if (m0 >= ptot) return;
  int e = 0;
  #pragma unroll
  for (int q = 0; q < 7; ++q) if (m0 >= off[q + 1]) e = q + 1;
  const int n0 = blockIdx.y * 64;

  const int tid = threadIdx.x, lane = tid & 63, wv = tid >> 6;
  const int wr = wv * 32;

  __shared__ __attribute__((aligned(1024))) char smem[49152];

  const char* aBase = (const char*)hbufT + (size_t)blockIdx.x * 48 * 16384;
  const char* bBase = (const char*)w2tT + (((size_t)e * 12 + blockIdx.y) * 48) * 8192;

  f32x4 acc[2][4];
  #pragma unroll
  for (int i = 0; i < 2; ++i)
    #pragma unroll
    for (int j = 0; j < 4; ++j)
      #pragma unroll
      for (int q = 0; q < 4; ++q) acc[i][j][q] = 0.0f;

  {
    const char* aS = aBase + (size_t)wv * 4096 + lane * 16;
    char* aD = smem + wv * 4096;
    const char* bS = bBase + (size_t)wv * 2048 + lane * 16;
    char* bD = smem + 32768 + wv * 2048;
    #pragma unroll
    for (int i = 0; i < 4; ++i) load16_lds(aS + i * 1024, aD + i * 1024);
    #pragma unroll
    for (int i = 0; i < 2; ++i) load16_lds(bS + i * 1024, bD + i * 1024);
  }
  __syncthreads();

  for (int kc = 0; kc < 48; ++kc) {
    const int cur = kc & 1;
    if (kc + 1 < 48) {
      const int nb = cur ^ 1;
      const char* aS = aBase + (size_t)(kc + 1) * 16384 + wv * 4096 + lane * 16;
      char* aD = smem + nb * 16384 + wv * 4096;
      const char* bS = bBase + (size_t)(kc + 1) * 8192 + wv * 2048 + lane * 16;
      char* bD = smem + 32768 + nb * 8192 + wv * 2048;
      #pragma unroll
      for (int i = 0; i < 4; ++i) load16_lds(aS + i * 1024, aD + i * 1024);
      #pragma unroll
      for (int i = 0; i < 2; ++i) load16_lds(bS + i * 1024, bD + i * 1024);
    }
    const char* A = smem + cur * 16384;
    const char* B = smem + 32768 + cur * 8192;
    #pragma unroll
    for (int kk = 0; kk < 2; ++kk) {
      bf16x8 af[2], bfr[4];
      #pragma unroll
      for (int f = 0; f < 2; ++f) {
        int row = wr + f * 16 + (lane & 15);
        int byte = row * 128 + kk * 64 + (lane >> 4) * 16;
        byte ^= (row & 7) << 4;
        af[f] = *(const bf16x8*)(A + byte);
      }
      #pragma unroll
      for (int f = 0; f < 4; ++f) {
        int row = f * 16 + (lane & 15);
        int byte = row * 128 + kk * 64 + (lane >> 4) * 16;
        byte ^= (row & 7) << 4;
        bfr[f] = *(const bf16x8*)(B + byte);
      }
      #pragma unroll
      for (int fm = 0; fm < 2; ++fm)
        #pragma unroll
        for (int fn = 0; fn < 4; ++fn)
          acc[fm][fn] = __builtin_amdgcn_mfma_f32_16x16x32_bf16(
              af[fm], bfr[fn], acc[fm][fn], 0, 0, 0);
    }
    __syncthreads();
  }

  // epilogue: bias + tprob scale -> f32 LDS tile [128][68] -> row scatter
  const int g = lane >> 4, ci = lane & 15;
  float b2v[4];
  #pragma unroll
  for (int fn = 0; fn < 4; ++fn) b2v[fn] = b2[e * CDIM + n0 + fn * 16 + ci];
  float tp[2][4];
  #pragma unroll
  for (int fm = 0; fm < 2; ++fm)
    #pragma unroll
    for (int rg = 0; rg < 4; ++rg)
      tp[fm][rg] = tpg[m0 + wr + fm * 16 + g * 4 + rg];

  #pragma unroll
  for (int fm = 0; fm < 2; ++fm)
    #pragma unroll
    for (int fn = 0; fn < 4; ++fn)
      #pragma unroll
      for (int rg = 0; rg < 4; ++rg) {
        int row = wr + fm * 16 + g * 4 + rg;
        int col = fn * 16 + ci;
        *(float*)(smem + row * 272 + col * 4) =
            (acc[fm][fn][rg] + b2v[fn]) * tp[fm][rg];
      }
  __syncthreads();

  const int myrow = tid >> 4, c16 = tid & 15;
  #pragma unroll
  for (int i = 0; i < 8; ++i) {
    int row = myrow + i * 16;
    int tokr = tokmap[m0 + row];
    f32x4 v = *(const f32x4*)(smem + row * 272 + c16 * 16);
    if (tokr >= 0)
      *(f32x4*)(y + (size_t)tokr * CDIM + n0 + c16 * 4) = v;
  }
}

// ---------------------------------------------------------------------------
extern "C" void kernel_launch(void* const* d_in, const int* in_sizes, int n_in,
                              void* d_out, int out_size, void* d_ws, size_t ws_size,
                              hipStream_t stream)
{
  const float* x  = (const float*)d_in[0];
  const float* Wr = (const float*)d_in[1];
  const float* W1 = (const float*)d_in[2];
  const float* b1 = (const float*)d_in[3];
  const float* W2 = (const float*)d_in[4];
  const float* b2 = (const float*)d_in[5];
  float* out = (float*)d_out;

  char* ws = (char*)d_ws;
  int*   counts     = (int*)(ws + WS_COUNTS);
  float* importance = (float*)(ws + WS_IMP);
  int*   off        = (int*)(ws + WS_OFF);
  float* tprob      = (float*)(ws + WS_TPROB);
  int*   bucket     = (int*)(ws + WS_BUCKET);
  int*   tokmap     = (int*)(ws + WS_TOKMAP);
  float* tpg        = (float*)(ws + WS_TPG);
  bf16*  xgT        = (bf16*)(ws + WS_XGT);
  bf16*  w1tT       = (bf16*)(ws + WS_W1T);
  bf16*  hbufT      = (bf16*)(ws + WS_HBUF);
  bf16*  w2tT       = (bf16*)(ws + WS_W2T);   // aliases xgT/w1tT, written post-ffn1

  hipMemsetAsync(ws, 0, 256, stream);

  router2<<<dim3(N_TOK / 4), 256, 0, stream>>>(x, Wr, tprob, bucket,
                                               counts, importance);
  aux_kernel<<<1, 64, 0, stream>>>(counts, importance,
                                   out + (size_t)N_TOK * CDIM, off);
  gather_kernel<<<dim3(2304), 256, 0, stream>>>(x, tprob, bucket, counts, off,
                                                xgT, tokmap, tpg);
  transpose_w<<<dim3(CDIM / 64, HDIM / 64, NEXP), 256, 0, stream>>>(
      W1, w1tT, CDIM, HDIM);
  ffn1_v3<<<dim3(72, 48), 256, 0, stream>>>(xgT, w1tT, b1, off, hbufT);
  transpose_w<<<dim3(HDIM / 64, CDIM / 64, NEXP), 256, 0, stream>>>(
      W2, w2tT, HDIM, CDIM);
  ffn2_v3<<<dim3(72, 12), 256, 0, stream>>>(hbufT, w2tT, b2, off,
                                            tokmap, tpg, out);
}

// Round 5
// 206.895 us; speedup vs baseline: 6.0837x; 1.5088x over previous
//
#include <hip/hip_runtime.h>
#include <hip/hip_bf16.h>
#include <cstdint>
#include <cmath>

#define N_TOK 8192
#define CDIM  768
#define HDIM  3072
#define NEXP  8
#define NBLK  256     // router/gather blocks, 32 tokens each

typedef __bf16 bf16;
typedef __bf16 bf16x4 __attribute__((ext_vector_type(4)));
typedef __bf16 bf16x8 __attribute__((ext_vector_type(8)));
typedef float  f32x4  __attribute__((ext_vector_type(4)));

// ws byte offsets
#define WS_BE      0u          // 8192 int
#define WS_TPROB   32768u      // 8192 f32
#define WS_CNTB    65536u      // 256*8 int
#define WS_IMPB    73728u      // 256*8 f32
#define WS_BASEB   81920u      // 256*8 int
#define WS_CNT     90112u      // 8 int
#define WS_OFF     90176u      // 9 int
#define WS_TOKMAP  98304u      // 9216 int
#define WS_TPG     137216u     // 9216 f32  -> ends 174080
#define WS_XGT     (1u<<20)    // 72*12*16384 = 14,155,776
#define WS_W1T     (16u<<20)   // 37,748,736 -> ends 54,525,952
#define WS_HBUF    (56u<<20)   // 72*48*16384 = 56,623,104 -> ends 115,343,360
#define WS_W2T     (1u<<20)    // aliases XGT/W1T, written after ffn1

__device__ __forceinline__ void load16_lds(const void* g, void* l) {
  __builtin_amdgcn_global_load_lds(
      (const __attribute__((address_space(1))) void*)g,
      (__attribute__((address_space(3))) void*)l, 16, 0, 0);
}

// ---------------------------------------------------------------------------
// Router: 256 blocks x 32 tokens, wave-per-token (8 tokens/wave).
// Router weights live in 96 VGPRs per lane. Zero global atomics.
// ---------------------------------------------------------------------------
__global__ __launch_bounds__(256) void router3(
    const float* __restrict__ x, const float* __restrict__ Wr,
    float* __restrict__ tprob, int* __restrict__ be_out,
    int* __restrict__ cnt_blk, float* __restrict__ imp_blk)
{
  const int tid = threadIdx.x, lane = tid & 63, wv = tid >> 6;
  const int b = blockIdx.x;
  __shared__ int cnt_l[NEXP];
  __shared__ float imp_l[4][NEXP];
  if (tid < NEXP) cnt_l[tid] = 0;

  // wreg[j*4+q][e] = Wr[c][e], c = j*256 + lane*4 + q
  float wreg[12][8];
  #pragma unroll
  for (int j = 0; j < 3; ++j)
    #pragma unroll
    for (int q = 0; q < 4; ++q) {
      const float4* p = (const float4*)(Wr + (size_t)(j * 256 + lane * 4 + q) * 8);
      float4 lo = p[0], hi = p[1];
      wreg[j*4+q][0] = lo.x; wreg[j*4+q][1] = lo.y;
      wreg[j*4+q][2] = lo.z; wreg[j*4+q][3] = lo.w;
      wreg[j*4+q][4] = hi.x; wreg[j*4+q][5] = hi.y;
      wreg[j*4+q][6] = hi.z; wreg[j*4+q][7] = hi.w;
    }

  float impacc[NEXP];
  #pragma unroll
  for (int e = 0; e < NEXP; ++e) impacc[e] = 0.0f;
  __syncthreads();

  #pragma unroll 1
  for (int t = 0; t < 8; ++t) {
    const int tok = b * 32 + wv * 8 + t;
    float4 xv[3];
    #pragma unroll
    for (int j = 0; j < 3; ++j)
      xv[j] = *(const float4*)(x + (size_t)tok * CDIM + j * 256 + lane * 4);

    float acc[NEXP];
    #pragma unroll
    for (int e = 0; e < NEXP; ++e) acc[e] = 0.0f;
    #pragma unroll
    for (int j = 0; j < 3; ++j) {
      const float xa[4] = {xv[j].x, xv[j].y, xv[j].z, xv[j].w};
      #pragma unroll
      for (int q = 0; q < 4; ++q)
        #pragma unroll
        for (int e = 0; e < NEXP; ++e)
          acc[e] = fmaf(xa[q], wreg[j*4+q][e], acc[e]);
    }
    #pragma unroll
    for (int e = 0; e < NEXP; ++e) {
      float v = acc[e];
      v += __shfl_xor(v, 1);  v += __shfl_xor(v, 2);  v += __shfl_xor(v, 4);
      v += __shfl_xor(v, 8);  v += __shfl_xor(v, 16); v += __shfl_xor(v, 32);
      acc[e] = v;
    }
    float m = acc[0]; int be = 0;
    #pragma unroll
    for (int e = 1; e < NEXP; ++e) if (acc[e] > m) { m = acc[e]; be = e; }
    float pr[NEXP]; float s = 0.0f;
    #pragma unroll
    for (int e = 0; e < NEXP; ++e) { pr[e] = __expf(acc[e] - m); s += pr[e]; }
    const float inv = 1.0f / s;
    #pragma unroll
    for (int e = 0; e < NEXP; ++e) impacc[e] += pr[e] * inv;
    if (lane == 0) {
      tprob[tok]  = pr[be] * inv;
      be_out[tok] = be;
      atomicAdd(&cnt_l[be], 1);          // LDS atomic
    }
  }

  if (lane == 0) {
    #pragma unroll
    for (int e = 0; e < NEXP; ++e) imp_l[wv][e] = impacc[e];
  }
  __syncthreads();
  if (tid < NEXP) {
    cnt_blk[b * NEXP + tid] = cnt_l[tid];
    imp_blk[b * NEXP + tid] =
        imp_l[0][tid] + imp_l[1][tid] + imp_l[2][tid] + imp_l[3][tid];
  }
}

// ---------------------------------------------------------------------------
// Scan: one block, 256 threads. Per-expert exclusive scan over 256 blocks,
// padded offsets, counts, importance, aux loss. No atomics anywhere.
// ---------------------------------------------------------------------------
__global__ __launch_bounds__(256) void scan_kernel(
    const int* __restrict__ cnt_blk, const float* __restrict__ imp_blk,
    int* __restrict__ counts, int* __restrict__ off,
    int* __restrict__ base_blk, float* __restrict__ out_aux)
{
  const int tid = threadIdx.x, lane = tid & 63, wv = tid >> 6;
  __shared__ int   wsum[NEXP][4];
  __shared__ float wimp[NEXP][4];
  __shared__ int   off_s[9];

  int pref[NEXP];
  #pragma unroll
  for (int e = 0; e < NEXP; ++e) {
    int v = cnt_blk[tid * NEXP + e];
    int inc = v;
    #pragma unroll
    for (int o = 1; o < 64; o <<= 1) {
      int n = __shfl_up(inc, o);
      if (lane >= o) inc += n;
    }
    if (lane == 63) wsum[e][wv] = inc;
    pref[e] = inc - v;

    float f = imp_blk[tid * NEXP + e];
    f += __shfl_xor(f, 1);  f += __shfl_xor(f, 2);  f += __shfl_xor(f, 4);
    f += __shfl_xor(f, 8);  f += __shfl_xor(f, 16); f += __shfl_xor(f, 32);
    if (lane == 0) wimp[e][wv] = f;
  }
  __syncthreads();
  if (tid == 0) {
    int o = 0; float aux = 0.0f;
    #pragma unroll
    for (int e = 0; e < NEXP; ++e) {
      int tot = wsum[e][0] + wsum[e][1] + wsum[e][2] + wsum[e][3];
      float im = wimp[e][0] + wimp[e][1] + wimp[e][2] + wimp[e][3];
      counts[e] = tot;
      aux += im * (float)tot;
      off_s[e] = o;
      o += (tot + 127) & ~127;
    }
    off_s[8] = o;
    out_aux[0] = (float)NEXP * aux / ((float)N_TOK * (float)N_TOK);
    for (int i = 0; i < 9; ++i) off[i] = off_s[i];
  }
  __syncthreads();
  #pragma unroll
  for (int e = 0; e < NEXP; ++e) {
    int wofs = 0;
    #pragma unroll
    for (int w = 0; w < 4; ++w) if (w < wv) wofs += wsum[e][w];
    base_blk[tid * NEXP + e] = off_s[e] + wofs + pref[e];
  }
}

// ---------------------------------------------------------------------------
// Gather: same 32-token blocking as router. Slot = scanned base + ballot rank
// (deterministic). Packs rows into xgT [tile][kc:12][128][64] swizzled bf16.
// ---------------------------------------------------------------------------
__global__ __launch_bounds__(256) void gather2(
    const float* __restrict__ x, const float* __restrict__ tprob,
    const int* __restrict__ be, const int* __restrict__ base_blk,
    bf16* __restrict__ xgT, int* __restrict__ tokmap, float* __restrict__ tpg)
{
  const int tid = threadIdx.x, lane = tid & 63, wv = tid >> 6;
  const int b = blockIdx.x;
  __shared__ int slot_l[32];

  if (wv == 0) {
    const int t = lane;
    const int bet = (t < 32) ? be[b * 32 + t] : -1;
    int slot = -1;
    #pragma unroll
    for (int e = 0; e < NEXP; ++e) {
      unsigned long long msk = __ballot(bet == e);
      if (bet == e) {
        int rank = __popcll(msk & ((1ull << lane) - 1ull));
        slot = base_blk[b * NEXP + e] + rank;
      }
    }
    if (t < 32) {
      slot_l[t] = slot;
      const int tok = b * 32 + t;
      tokmap[slot] = tok;
      tpg[slot] = tprob[tok];
    }
  }
  __syncthreads();

  #pragma unroll 1
  for (int t8 = 0; t8 < 8; ++t8) {
    const int t = wv * 8 + t8;
    const int slot = slot_l[t];
    const int tok = b * 32 + t;
    const int tile = slot >> 7, r = slot & 127;
    #pragma unroll
    for (int j = 0; j < 3; ++j) {
      const int col = j * 256 + lane * 4;
      const int kc = col >> 6, cw = col & 63;
      float4 v = *(const float4*)(x + (size_t)tok * CDIM + col);
      bf16x4 o;
      o[0] = (bf16)v.x; o[1] = (bf16)v.y; o[2] = (bf16)v.z; o[3] = (bf16)v.w;
      char* dst = (char*)xgT + (((size_t)tile * 12 + kc) * 128 + r) * 128
                  + ((cw * 2) ^ ((r & 7) << 4));
      *(bf16x4*)dst = o;
    }
  }
}

// ---------------------------------------------------------------------------
// W [E][R][S] fp32 -> tiled bf16 [E][S/64][R/64][64][64], swizzled rows.
// ---------------------------------------------------------------------------
__global__ __launch_bounds__(256) void transpose_w(
    const float* __restrict__ W, bf16* __restrict__ WT, int R, int S)
{
  __shared__ float t[64][65];
  const int r0 = blockIdx.x * 64, s0 = blockIdx.y * 64, e = blockIdx.z;
  const float* We = W + (size_t)e * R * S;
  const int NT = S >> 6, NK = R >> 6;
  char* outT = (char*)WT + (((size_t)e * NT + (s0 >> 6)) * NK + (r0 >> 6)) * 8192;
  const int tid = threadIdx.x, lr = tid >> 4, lc4 = tid & 15;

  #pragma unroll
  for (int j = 0; j < 4; ++j) {
    int r = lr + j * 16;
    float4 v = *(const float4*)(We + (size_t)(r0 + r) * S + s0 + lc4 * 4);
    t[r][lc4 * 4 + 0] = v.x; t[r][lc4 * 4 + 1] = v.y;
    t[r][lc4 * 4 + 2] = v.z; t[r][lc4 * 4 + 3] = v.w;
  }
  __syncthreads();
  #pragma unroll
  for (int j = 0; j < 4; ++j) {
    int sI = lr + j * 16;
    bf16x4 o;
    #pragma unroll
    for (int q = 0; q < 4; ++q) o[q] = (bf16)t[lc4 * 4 + q][sI];
    *(bf16x4*)(outT + sI * 128 + ((lc4 * 8) ^ ((sI & 7) << 4))) = o;
  }
}

// ---------------------------------------------------------------------------
// Grouped GEMM, m97 shape: BM=128, BN=128, BK=64, 4 waves (2x2), per-wave
// 64x64, dbuf LDS (64 KB). All staging = contiguous 1 KB global_load_lds.
// NKC = K/64 chunks, NCHN = N/64 chunks of the weight layout.
// ---------------------------------------------------------------------------
template<int NKC, int NCHN, bool GELU>
__global__ __launch_bounds__(256) void ffn_t(
    const bf16* __restrict__ Abuf, const bf16* __restrict__ Wt,
    const float* __restrict__ bias, const int* __restrict__ off,
    const int* __restrict__ tokmap, const float* __restrict__ tpg,
    bf16* __restrict__ hbufT, float* __restrict__ y)
{
  const int ptot = off[8];
  const int m0 = blockIdx.x * 128;
  if (m0 >= ptot) return;
  int e = 0;
  #pragma unroll
  for (int q = 0; q < 7; ++q) if (m0 >= off[q + 1]) e = q + 1;
  const int by = blockIdx.y;

  const int tid = threadIdx.x, lane = tid & 63, wv = tid >> 6;
  const int wr = (wv >> 1) * 64;      // wave row
  const int wc = (wv & 1) * 64;       // wave col

  __shared__ __attribute__((aligned(1024))) char smem[65536];
  // A0 @0, A1 @16K, B0 @32K, B1 @48K

  const char* aBase = (const char*)Abuf + (size_t)blockIdx.x * NKC * 16384;
  const char* bBase0 = (const char*)Wt +
      (((size_t)e * NCHN + by * 2 + (wv >> 1)) * NKC) * 8192 + (wv & 1) * 4096;

  f32x4 acc[4][4];
  #pragma unroll
  for (int i = 0; i < 4; ++i)
    #pragma unroll
    for (int j = 0; j < 4; ++j)
      #pragma unroll
      for (int q = 0; q < 4; ++q) acc[i][j][q] = 0.0f;

  // prologue: stage kc=0 into buf0
  {
    const char* aS = aBase + wv * 4096 + lane * 16;
    const char* bS = bBase0 + lane * 16;
    #pragma unroll
    for (int i = 0; i < 4; ++i) {
      load16_lds(aS + i * 1024, smem + wv * 4096 + i * 1024);
      load16_lds(bS + i * 1024, smem + 32768 + wv * 4096 + i * 1024);
    }
  }
  __syncthreads();

  for (int kc = 0; kc < NKC; ++kc) {
    const int cur = kc & 1;
    if (kc + 1 < NKC) {
      const int nb = cur ^ 1;
      const char* aS = aBase + (size_t)(kc + 1) * 16384 + wv * 4096 + lane * 16;
      const char* bS = bBase0 + (size_t)(kc + 1) * 8192 + lane * 16;
      #pragma unroll
      for (int i = 0; i < 4; ++i) {
        load16_lds(aS + i * 1024, smem + nb * 16384 + wv * 4096 + i * 1024);
        load16_lds(bS + i * 1024, smem + 32768 + nb * 16384 + wv * 4096 + i * 1024);
      }
    }
    const char* A = smem + cur * 16384;
    const char* B = smem + 32768 + cur * 16384;
    #pragma unroll
    for (int kk = 0; kk < 2; ++kk) {
      bf16x8 af[4], bfr[4];
      #pragma unroll
      for (int f = 0; f < 4; ++f) {
        int row  = wr + f * 16 + (lane & 15);
        int byte = row * 128 + kk * 64 + (lane >> 4) * 16;
        byte ^= (row & 7) << 4;
        af[f] = *(const bf16x8*)(A + byte);
      }
      #pragma unroll
      for (int f = 0; f < 4; ++f) {
        int row  = wc + f * 16 + (lane & 15);
        int byte = row * 128 + kk * 64 + (lane >> 4) * 16;
        byte ^= (row & 7) << 4;
        bfr[f] = *(const bf16x8*)(B + byte);
      }
      #pragma unroll
      for (int fm = 0; fm < 4; ++fm)
        #pragma unroll
        for (int fn = 0; fn < 4; ++fn)
          acc[fm][fn] = __builtin_amdgcn_mfma_f32_16x16x32_bf16(
              af[fm], bfr[fn], acc[fm][fn], 0, 0, 0);
    }
    __syncthreads();
  }

  const int g = lane >> 4, ci = lane & 15;
  float bv[4];
  #pragma unroll
  for (int fn = 0; fn < 4; ++fn)
    bv[fn] = bias[e * (NCHN * 64) + by * 128 + wc + fn * 16 + ci];

  if (GELU) {
    // bias + tanh-GELU -> swizzled bf16 C tile (32 KB) -> linear copy to hbufT
    #pragma unroll
    for (int fm = 0; fm < 4; ++fm)
      #pragma unroll
      for (int fn = 0; fn < 4; ++fn)
        #pragma unroll
        for (int rg = 0; rg < 4; ++rg) {
          int row = wr + fm * 16 + g * 4 + rg;
          int col = wc + fn * 16 + ci;
          float v = acc[fm][fn][rg] + bv[fn];
          float t3 = v + 0.044715f * v * v * v;
          float gel = v / (1.0f + __expf(-1.5957691216f * t3));
          int chunk = col >> 6, cw = col & 63;
          int byte = chunk * 16384 + row * 128 + ((cw * 2) ^ ((row & 7) << 4));
          *(bf16*)(smem + byte) = (bf16)gel;
        }
    __syncthreads();
    char* hdst = (char*)hbufT + ((size_t)blockIdx.x * 48 + by * 2) * 16384;
    #pragma unroll
    for (int i = 0; i < 8; ++i) {
      int bo = (i * 256 + tid) * 16;
      *(f32x4*)(hdst + bo) = *(const f32x4*)(smem + bo);
    }
  } else {
    // bias + tprob -> two staged half-tiles [128][68] f32 -> coalesced scatter
    float tp[4][4];
    #pragma unroll
    for (int fm = 0; fm < 4; ++fm)
      #pragma unroll
      for (int rg = 0; rg < 4; ++rg)
        tp[fm][rg] = tpg[m0 + wr + fm * 16 + g * 4 + rg];
    float* smemf = (float*)smem;
    #pragma unroll
    for (int h = 0; h < 2; ++h) {
      if ((wv & 1) == h) {
        #pragma unroll
        for (int fm = 0; fm < 4; ++fm)
          #pragma unroll
          for (int fn = 0; fn < 4; ++fn)
            #pragma unroll
            for (int rg = 0; rg < 4; ++rg) {
              int row = wr + fm * 16 + g * 4 + rg;
              int cl  = fn * 16 + ci;
              smemf[row * 68 + cl] = (acc[fm][fn][rg] + bv[fn]) * tp[fm][rg];
            }
      }
      __syncthreads();
      // full half-tile: 128 rows x 16 f32x4 = 2048 vec4s, 8 per thread
      #pragma unroll
      for (int it = 0; it < 8; ++it) {
        int lin = it * 256 + tid;
        int row = lin >> 4;          // 0..127
        int c4  = lin & 15;          // 0..15
        int tokr = tokmap[m0 + row];
        f32x4 v = *(const f32x4*)(smemf + row * 68 + c4 * 4);
        if (tokr >= 0)
          *(f32x4*)(y + (size_t)tokr * CDIM + by * 128 + h * 64 + c4 * 4) = v;
      }
      __syncthreads();
    }
  }
}

// ---------------------------------------------------------------------------
extern "C" void kernel_launch(void* const* d_in, const int* in_sizes, int n_in,
                              void* d_out, int out_size, void* d_ws, size_t ws_size,
                              hipStream_t stream)
{
  const float* x  = (const float*)d_in[0];
  const float* Wr = (const float*)d_in[1];
  const float* W1 = (const float*)d_in[2];
  const float* b1 = (const float*)d_in[3];
  const float* W2 = (const float*)d_in[4];
  const float* b2 = (const float*)d_in[5];
  float* out = (float*)d_out;

  char* ws = (char*)d_ws;
  int*   be         = (int*)(ws + WS_BE);
  float* tprob      = (float*)(ws + WS_TPROB);
  int*   cnt_blk    = (int*)(ws + WS_CNTB);
  float* imp_blk    = (float*)(ws + WS_IMPB);
  int*   base_blk   = (int*)(ws + WS_BASEB);
  int*   counts     = (int*)(ws + WS_CNT);
  int*   off        = (int*)(ws + WS_OFF);
  int*   tokmap     = (int*)(ws + WS_TOKMAP);
  float* tpg        = (float*)(ws + WS_TPG);
  bf16*  xgT        = (bf16*)(ws + WS_XGT);
  bf16*  w1tT       = (bf16*)(ws + WS_W1T);
  bf16*  hbufT      = (bf16*)(ws + WS_HBUF);
  bf16*  w2tT       = (bf16*)(ws + WS_W2T);   // written after ffn1

  hipMemsetAsync(tokmap, 0xFF, 9216 * sizeof(int), stream);

  router3<<<dim3(NBLK), 256, 0, stream>>>(x, Wr, tprob, be, cnt_blk, imp_blk);
  scan_kernel<<<dim3(1), 256, 0, stream>>>(cnt_blk, imp_blk, counts, off,
                                           base_blk, out + (size_t)N_TOK * CDIM);
  gather2<<<dim3(NBLK), 256, 0, stream>>>(x, tprob, be, base_blk,
                                          xgT, tokmap, tpg);
  transpose_w<<<dim3(CDIM / 64, HDIM / 64, NEXP), 256, 0, stream>>>(
      W1, w1tT, CDIM, HDIM);
  ffn_t<12, 48, true><<<dim3(72, HDIM / 128), 256, 0, stream>>>(
      xgT, w1tT, b1, off, tokmap, tpg, hbufT, nullptr);
  transpose_w<<<dim3(HDIM / 64, CDIM / 64, NEXP), 256, 0, stream>>>(
      W2, w2tT, HDIM, CDIM);
  ffn_t<48, 12, false><<<dim3(72, CDIM / 128), 256, 0, stream>>>(
      hbufT, w2tT, b2, off, tokmap, tpg, nullptr, out);
}

// Round 6
// 197.027 us; speedup vs baseline: 6.3884x; 1.0501x over previous
//
#include <hip/hip_runtime.h>
#include <hip/hip_bf16.h>
#include <cstdint>
#include <cmath>

#define N_TOK 8192
#define CDIM  768
#define HDIM  3072
#define NEXP  8
#define NBLK  256     // router/gather blocks, 32 tokens each

typedef __bf16 bf16;
typedef __bf16 bf16x4 __attribute__((ext_vector_type(4)));
typedef __bf16 bf16x8 __attribute__((ext_vector_type(8)));
typedef float  f32x4  __attribute__((ext_vector_type(4)));

// ws byte offsets
#define WS_BE      0u          // 8192 int
#define WS_TPROB   32768u      // 8192 f32
#define WS_CNTB    65536u      // 256*8 int
#define WS_IMPB    73728u      // 256*8 f32
#define WS_BASEB   81920u      // 256*8 int
#define WS_CNT     90112u      // 8 int
#define WS_OFF     90176u      // 9 int
#define WS_TOKMAP  98304u      // 9216 int
#define WS_TPG     137216u     // 9216 f32  -> ends 174080
#define WS_XGT     (1u<<20)    // 72*12*16384 = 14,155,776
#define WS_W1T     (16u<<20)   // 37,748,736 -> ends 54,525,952
#define WS_HBUF    (56u<<20)   // 72*48*16384 = 56,623,104 -> ends 115,343,360
#define WS_W2T     (1u<<20)    // aliases XGT/W1T, written after ffn1

__device__ __forceinline__ void load16_lds(const void* g, void* l) {
  __builtin_amdgcn_global_load_lds(
      (const __attribute__((address_space(1))) void*)g,
      (__attribute__((address_space(3))) void*)l, 16, 0, 0);
}

// ---------------------------------------------------------------------------
// Router: 256 blocks x 32 tokens, wave-per-token (8 tokens/wave).
// Router weights live in 96 VGPRs per lane. Zero global atomics.
// ---------------------------------------------------------------------------
__global__ __launch_bounds__(256) void router3(
    const float* __restrict__ x, const float* __restrict__ Wr,
    float* __restrict__ tprob, int* __restrict__ be_out,
    int* __restrict__ cnt_blk, float* __restrict__ imp_blk)
{
  const int tid = threadIdx.x, lane = tid & 63, wv = tid >> 6;
  const int b = blockIdx.x;
  __shared__ int cnt_l[NEXP];
  __shared__ float imp_l[4][NEXP];
  if (tid < NEXP) cnt_l[tid] = 0;

  // wreg[j*4+q][e] = Wr[c][e], c = j*256 + lane*4 + q
  float wreg[12][8];
  #pragma unroll
  for (int j = 0; j < 3; ++j)
    #pragma unroll
    for (int q = 0; q < 4; ++q) {
      const float4* p = (const float4*)(Wr + (size_t)(j * 256 + lane * 4 + q) * 8);
      float4 lo = p[0], hi = p[1];
      wreg[j*4+q][0] = lo.x; wreg[j*4+q][1] = lo.y;
      wreg[j*4+q][2] = lo.z; wreg[j*4+q][3] = lo.w;
      wreg[j*4+q][4] = hi.x; wreg[j*4+q][5] = hi.y;
      wreg[j*4+q][6] = hi.z; wreg[j*4+q][7] = hi.w;
    }

  float impacc[NEXP];
  #pragma unroll
  for (int e = 0; e < NEXP; ++e) impacc[e] = 0.0f;
  __syncthreads();

  #pragma unroll 1
  for (int t = 0; t < 8; ++t) {
    const int tok = b * 32 + wv * 8 + t;
    float4 xv[3];
    #pragma unroll
    for (int j = 0; j < 3; ++j)
      xv[j] = *(const float4*)(x + (size_t)tok * CDIM + j * 256 + lane * 4);

    float acc[NEXP];
    #pragma unroll
    for (int e = 0; e < NEXP; ++e) acc[e] = 0.0f;
    #pragma unroll
    for (int j = 0; j < 3; ++j) {
      const float xa[4] = {xv[j].x, xv[j].y, xv[j].z, xv[j].w};
      #pragma unroll
      for (int q = 0; q < 4; ++q)
        #pragma unroll
        for (int e = 0; e < NEXP; ++e)
          acc[e] = fmaf(xa[q], wreg[j*4+q][e], acc[e]);
    }
    #pragma unroll
    for (int e = 0; e < NEXP; ++e) {
      float v = acc[e];
      v += __shfl_xor(v, 1);  v += __shfl_xor(v, 2);  v += __shfl_xor(v, 4);
      v += __shfl_xor(v, 8);  v += __shfl_xor(v, 16); v += __shfl_xor(v, 32);
      acc[e] = v;
    }
    float m = acc[0]; int be = 0;
    #pragma unroll
    for (int e = 1; e < NEXP; ++e) if (acc[e] > m) { m = acc[e]; be = e; }
    float pr[NEXP]; float s = 0.0f;
    #pragma unroll
    for (int e = 0; e < NEXP; ++e) { pr[e] = __expf(acc[e] - m); s += pr[e]; }
    const float inv = 1.0f / s;
    #pragma unroll
    for (int e = 0; e < NEXP; ++e) impacc[e] += pr[e] * inv;
    if (lane == 0) {
      tprob[tok]  = pr[be] * inv;
      be_out[tok] = be;
      atomicAdd(&cnt_l[be], 1);          // LDS atomic
    }
  }

  if (lane == 0) {
    #pragma unroll
    for (int e = 0; e < NEXP; ++e) imp_l[wv][e] = impacc[e];
  }
  __syncthreads();
  if (tid < NEXP) {
    cnt_blk[b * NEXP + tid] = cnt_l[tid];
    imp_blk[b * NEXP + tid] =
        imp_l[0][tid] + imp_l[1][tid] + imp_l[2][tid] + imp_l[3][tid];
  }
}

// ---------------------------------------------------------------------------
// Scan: one block, 256 threads. Per-expert exclusive scan over 256 blocks,
// padded offsets, counts, importance, aux loss. No atomics anywhere.
// ---------------------------------------------------------------------------
__global__ __launch_bounds__(256) void scan_kernel(
    const int* __restrict__ cnt_blk, const float* __restrict__ imp_blk,
    int* __restrict__ counts, int* __restrict__ off,
    int* __restrict__ base_blk, float* __restrict__ out_aux)
{
  const int tid = threadIdx.x, lane = tid & 63, wv = tid >> 6;
  __shared__ int   wsum[NEXP][4];
  __shared__ float wimp[NEXP][4];
  __shared__ int   off_s[9];

  int pref[NEXP];
  #pragma unroll
  for (int e = 0; e < NEXP; ++e) {
    int v = cnt_blk[tid * NEXP + e];
    int inc = v;
    #pragma unroll
    for (int o = 1; o < 64; o <<= 1) {
      int n = __shfl_up(inc, o);
      if (lane >= o) inc += n;
    }
    if (lane == 63) wsum[e][wv] = inc;
    pref[e] = inc - v;

    float f = imp_blk[tid * NEXP + e];
    f += __shfl_xor(f, 1);  f += __shfl_xor(f, 2);  f += __shfl_xor(f, 4);
    f += __shfl_xor(f, 8);  f += __shfl_xor(f, 16); f += __shfl_xor(f, 32);
    if (lane == 0) wimp[e][wv] = f;
  }
  __syncthreads();
  if (tid == 0) {
    int o = 0; float aux = 0.0f;
    #pragma unroll
    for (int e = 0; e < NEXP; ++e) {
      int tot = wsum[e][0] + wsum[e][1] + wsum[e][2] + wsum[e][3];
      float im = wimp[e][0] + wimp[e][1] + wimp[e][2] + wimp[e][3];
      counts[e] = tot;
      aux += im * (float)tot;
      off_s[e] = o;
      o += (tot + 127) & ~127;
    }
    off_s[8] = o;
    out_aux[0] = (float)NEXP * aux / ((float)N_TOK * (float)N_TOK);
    for (int i = 0; i < 9; ++i) off[i] = off_s[i];
  }
  __syncthreads();
  #pragma unroll
  for (int e = 0; e < NEXP; ++e) {
    int wofs = 0;
    #pragma unroll
    for (int w = 0; w < 4; ++w) if (w < wv) wofs += wsum[e][w];
    base_blk[tid * NEXP + e] = off_s[e] + wofs + pref[e];
  }
}

// ---------------------------------------------------------------------------
// Gather: same 32-token blocking as router. Slot = scanned base + ballot rank
// (deterministic). Packs rows into xgT [tile][kc:12][128][64] swizzled bf16.
// ---------------------------------------------------------------------------
__global__ __launch_bounds__(256) void gather2(
    const float* __restrict__ x, const float* __restrict__ tprob,
    const int* __restrict__ be, const int* __restrict__ base_blk,
    bf16* __restrict__ xgT, int* __restrict__ tokmap, float* __restrict__ tpg)
{
  const int tid = threadIdx.x, lane = tid & 63, wv = tid >> 6;
  const int b = blockIdx.x;
  __shared__ int slot_l[32];

  if (wv == 0) {
    const int t = lane;
    const int bet = (t < 32) ? be[b * 32 + t] : -1;
    int slot = -1;
    #pragma unroll
    for (int e = 0; e < NEXP; ++e) {
      unsigned long long msk = __ballot(bet == e);
      if (bet == e) {
        int rank = __popcll(msk & ((1ull << lane) - 1ull));
        slot = base_blk[b * NEXP + e] + rank;
      }
    }
    if (t < 32) {
      slot_l[t] = slot;
      const int tok = b * 32 + t;
      tokmap[slot] = tok;
      tpg[slot] = tprob[tok];
    }
  }
  __syncthreads();

  #pragma unroll 1
  for (int t8 = 0; t8 < 8; ++t8) {
    const int t = wv * 8 + t8;
    const int slot = slot_l[t];
    const int tok = b * 32 + t;
    const int tile = slot >> 7, r = slot & 127;
    #pragma unroll
    for (int j = 0; j < 3; ++j) {
      const int col = j * 256 + lane * 4;
      const int kc = col >> 6, cw = col & 63;
      float4 v = *(const float4*)(x + (size_t)tok * CDIM + col);
      bf16x4 o;
      o[0] = (bf16)v.x; o[1] = (bf16)v.y; o[2] = (bf16)v.z; o[3] = (bf16)v.w;
      char* dst = (char*)xgT + (((size_t)tile * 12 + kc) * 128 + r) * 128
                  + ((cw * 2) ^ ((r & 7) << 4));
      *(bf16x4*)dst = o;
    }
  }
}

// ---------------------------------------------------------------------------
// W [E][R][S] fp32 -> tiled bf16 [E][S/64][R/64][64][64], swizzled rows.
// ---------------------------------------------------------------------------
__global__ __launch_bounds__(256) void transpose_w(
    const float* __restrict__ W, bf16* __restrict__ WT, int R, int S)
{
  __shared__ float t[64][65];
  const int r0 = blockIdx.x * 64, s0 = blockIdx.y * 64, e = blockIdx.z;
  const float* We = W + (size_t)e * R * S;
  const int NT = S >> 6, NK = R >> 6;
  char* outT = (char*)WT + (((size_t)e * NT + (s0 >> 6)) * NK + (r0 >> 6)) * 8192;
  const int tid = threadIdx.x, lr = tid >> 4, lc4 = tid & 15;

  #pragma unroll
  for (int j = 0; j < 4; ++j) {
    int r = lr + j * 16;
    float4 v = *(const float4*)(We + (size_t)(r0 + r) * S + s0 + lc4 * 4);
    t[r][lc4 * 4 + 0] = v.x; t[r][lc4 * 4 + 1] = v.y;
    t[r][lc4 * 4 + 2] = v.z; t[r][lc4 * 4 + 3] = v.w;
  }
  __syncthreads();
  #pragma unroll
  for (int j = 0; j < 4; ++j) {
    int sI = lr + j * 16;
    bf16x4 o;
    #pragma unroll
    for (int q = 0; q < 4; ++q) o[q] = (bf16)t[lc4 * 4 + q][sI];
    *(bf16x4*)(outT + sI * 128 + ((lc4 * 8) ^ ((sI & 7) << 4))) = o;
  }
}

// ---------------------------------------------------------------------------
// Grouped GEMM, m97 structure: BM=128, BN=128, BK=64, 4 waves (2x2),
// SINGLE-buffer 32 KB LDS, 2 barriers per K-step -> 5 blocks/CU co-resident.
// XCD-chunked tile remap: dispatch id % 8 owns a contiguous 9-wide x-range.
// ---------------------------------------------------------------------------
template<int NKC, int NCHN, bool GELU>
__global__ __launch_bounds__(256) void ffn_t(
    const bf16* __restrict__ Abuf, const bf16* __restrict__ Wt,
    const float* __restrict__ bias, const int* __restrict__ off,
    const int* __restrict__ tokmap, const float* __restrict__ tpg,
    bf16* __restrict__ hbufT, float* __restrict__ y)
{
  // XCD-aware remap: bid%8 = XCD chunk; chunk covers x in [9c, 9c+9) x all y.
  const int bid = blockIdx.x + blockIdx.y * 72;
  const int c  = bid & 7;
  const int r2 = bid >> 3;
  const int bx = c * 9 + (r2 % 9);
  const int by = r2 / 9;

  const int ptot = off[8];
  const int m0 = bx * 128;
  if (m0 >= ptot) return;
  int e = 0;
  #pragma unroll
  for (int q = 0; q < 7; ++q) if (m0 >= off[q + 1]) e = q + 1;

  const int tid = threadIdx.x, lane = tid & 63, wv = tid >> 6;
  const int wr = (wv >> 1) * 64;      // wave row
  const int wc = (wv & 1) * 64;      // wave col

  __shared__ __attribute__((aligned(1024))) char smem[32768];
  // A tile @0 (16K), B tile @16K

  const char* aBase = (const char*)Abuf + (size_t)bx * NKC * 16384;
  const char* bBase0 = (const char*)Wt +
      (((size_t)e * NCHN + by * 2 + (wv >> 1)) * NKC) * 8192 + (wv & 1) * 4096;

  f32x4 acc[4][4];
  #pragma unroll
  for (int i = 0; i < 4; ++i)
    #pragma unroll
    for (int j = 0; j < 4; ++j)
      #pragma unroll
      for (int q = 0; q < 4; ++q) acc[i][j][q] = 0.0f;

  for (int kc = 0; kc < NKC; ++kc) {
    __syncthreads();   // previous compute done reading smem
    {
      const char* aS = aBase + (size_t)kc * 16384 + wv * 4096 + lane * 16;
      const char* bS = bBase0 + (size_t)kc * 8192 + lane * 16;
      #pragma unroll
      for (int i = 0; i < 4; ++i) {
        load16_lds(aS + i * 1024, smem + wv * 4096 + i * 1024);
        load16_lds(bS + i * 1024, smem + 16384 + wv * 4096 + i * 1024);
      }
    }
    __syncthreads();   // vmcnt(0) drain: tile resident
    #pragma unroll
    for (int kk = 0; kk < 2; ++kk) {
      bf16x8 af[4], bfr[4];
      #pragma unroll
      for (int f = 0; f < 4; ++f) {
        int row  = wr + f * 16 + (lane & 15);
        int byte = row * 128 + kk * 64 + (lane >> 4) * 16;
        byte ^= (row & 7) << 4;
        af[f] = *(const bf16x8*)(smem + byte);
      }
      #pragma unroll
      for (int f = 0; f < 4; ++f) {
        int row  = wc + f * 16 + (lane & 15);
        int byte = row * 128 + kk * 64 + (lane >> 4) * 16;
        byte ^= (row & 7) << 4;
        bfr[f] = *(const bf16x8*)(smem + 16384 + byte);
      }
      #pragma unroll
      for (int fm = 0; fm < 4; ++fm)
        #pragma unroll
        for (int fn = 0; fn < 4; ++fn)
          acc[fm][fn] = __builtin_amdgcn_mfma_f32_16x16x32_bf16(
              af[fm], bfr[fn], acc[fm][fn], 0, 0, 0);
    }
  }
  __syncthreads();     // all ds_reads done before epilogue reuses smem

  const int g = lane >> 4, ci = lane & 15;
  float bv[4];
  #pragma unroll
  for (int fn = 0; fn < 4; ++fn)
    bv[fn] = bias[e * (NCHN * 64) + by * 128 + wc + fn * 16 + ci];

  if (GELU) {
    // bias + tanh-GELU -> swizzled bf16 C tile (exactly 32 KB) -> linear copy
    #pragma unroll
    for (int fm = 0; fm < 4; ++fm)
      #pragma unroll
      for (int fn = 0; fn < 4; ++fn)
        #pragma unroll
        for (int rg = 0; rg < 4; ++rg) {
          int row = wr + fm * 16 + g * 4 + rg;
          int col = wc + fn * 16 + ci;
          float v = acc[fm][fn][rg] + bv[fn];
          float t3 = v + 0.044715f * v * v * v;
          float gel = v / (1.0f + __expf(-1.5957691216f * t3));
          int chunk = col >> 6, cw = col & 63;
          int byte = chunk * 16384 + row * 128 + ((cw * 2) ^ ((row & 7) << 4));
          *(bf16*)(smem + byte) = (bf16)gel;
        }
    __syncthreads();
    char* hdst = (char*)hbufT + ((size_t)bx * 48 + by * 2) * 16384;
    #pragma unroll
    for (int i = 0; i < 8; ++i) {
      int bo = (i * 256 + tid) * 16;
      *(f32x4*)(hdst + bo) = *(const f32x4*)(smem + bo);
    }
  } else {
    // bias + tprob -> two 64-row x 128-col f32 phases -> coalesced scatter
    float tp[4][4];
    #pragma unroll
    for (int fm = 0; fm < 4; ++fm)
      #pragma unroll
      for (int rg = 0; rg < 4; ++rg)
        tp[fm][rg] = tpg[m0 + wr + fm * 16 + g * 4 + rg];
    float* smemf = (float*)smem;
    #pragma unroll
    for (int rr = 0; rr < 2; ++rr) {
      if ((wv >> 1) == rr) {
        #pragma unroll
        for (int fm = 0; fm < 4; ++fm)
          #pragma unroll
          for (int fn = 0; fn < 4; ++fn)
            #pragma unroll
            for (int rg = 0; rg < 4; ++rg) {
              int row = fm * 16 + g * 4 + rg;          // 0..63 local
              int col = wc + fn * 16 + ci;             // 0..127
              smemf[row * 128 + col] = (acc[fm][fn][rg] + bv[fn]) * tp[fm][rg];
            }
      }
      __syncthreads();
      // 64 rows x 32 f32x4 = 2048 vec4s, 8 per thread
      #pragma unroll
      for (int it = 0; it < 8; ++it) {
        int lin = it * 256 + tid;
        int row = lin >> 5;          // 0..63 local
        int c4  = lin & 31;          // 0..31
        int tokr = tokmap[m0 + rr * 64 + row];
        f32x4 v = *(const f32x4*)(smemf + row * 128 + c4 * 4);
        if (tokr >= 0)
          *(f32x4*)(y + (size_t)tokr * CDIM + by * 128 + c4 * 4) = v;
      }
      __syncthreads();
    }
  }
}

// ---------------------------------------------------------------------------
extern "C" void kernel_launch(void* const* d_in, const int* in_sizes, int n_in,
                              void* d_out, int out_size, void* d_ws, size_t ws_size,
                              hipStream_t stream)
{
  const float* x  = (const float*)d_in[0];
  const float* Wr = (const float*)d_in[1];
  const float* W1 = (const float*)d_in[2];
  const float* b1 = (const float*)d_in[3];
  const float* W2 = (const float*)d_in[4];
  const float* b2 = (const float*)d_in[5];
  float* out = (float*)d_out;

  char* ws = (char*)d_ws;
  int*   be         = (int*)(ws + WS_BE);
  float* tprob      = (float*)(ws + WS_TPROB);
  int*   cnt_blk    = (int*)(ws + WS_CNTB);
  float* imp_blk    = (float*)(ws + WS_IMPB);
  int*   base_blk   = (int*)(ws + WS_BASEB);
  int*   counts     = (int*)(ws + WS_CNT);
  int*   off        = (int*)(ws + WS_OFF);
  int*   tokmap     = (int*)(ws + WS_TOKMAP);
  float* tpg        = (float*)(ws + WS_TPG);
  bf16*  xgT        = (bf16*)(ws + WS_XGT);
  bf16*  w1tT       = (bf16*)(ws + WS_W1T);
  bf16*  hbufT      = (bf16*)(ws + WS_HBUF);
  bf16*  w2tT       = (bf16*)(ws + WS_W2T);   // written after ffn1

  hipMemsetAsync(tokmap, 0xFF, 9216 * sizeof(int), stream);

  router3<<<dim3(NBLK), 256, 0, stream>>>(x, Wr, tprob, be, cnt_blk, imp_blk);
  scan_kernel<<<dim3(1), 256, 0, stream>>>(cnt_blk, imp_blk, counts, off,
                                           base_blk, out + (size_t)N_TOK * CDIM);
  gather2<<<dim3(NBLK), 256, 0, stream>>>(x, tprob, be, base_blk,
                                          xgT, tokmap, tpg);
  transpose_w<<<dim3(CDIM / 64, HDIM / 64, NEXP), 256, 0, stream>>>(
      W1, w1tT, CDIM, HDIM);
  ffn_t<12, 48, true><<<dim3(72, HDIM / 128), 256, 0, stream>>>(
      xgT, w1tT, b1, off, tokmap, tpg, hbufT, nullptr);
  transpose_w<<<dim3(HDIM / 64, CDIM / 64, NEXP), 256, 0, stream>>>(
      W2, w2tT, HDIM, CDIM);
  ffn_t<48, 12, false><<<dim3(72, CDIM / 128), 256, 0, stream>>>(
      hbufT, w2tT, b2, off, tokmap, tpg, nullptr, out);
}

// Round 7
// 188.800 us; speedup vs baseline: 6.6667x; 1.0436x over previous
//
#include <hip/hip_runtime.h>
#include <hip/hip_bf16.h>
#include <cstdint>
#include <cmath>

#define N_TOK 8192
#define CDIM  768
#define HDIM  3072
#define NEXP  8
#define NBLK  256     // router/gather blocks, 32 tokens each

typedef __bf16 bf16;
typedef __bf16 bf16x4 __attribute__((ext_vector_type(4)));
typedef __bf16 bf16x8 __attribute__((ext_vector_type(8)));
typedef float  f32x4  __attribute__((ext_vector_type(4)));

// ws byte offsets
#define WS_BE      0u          // 8192 int
#define WS_TPROB   32768u      // 8192 f32
#define WS_CNTB    65536u      // 256*8 int
#define WS_IMPB    73728u      // 256*8 f32
#define WS_BASEB   81920u      // 256*8 int
#define WS_CNT     90112u      // 8 int
#define WS_OFF     90176u      // 9 int
#define WS_TOKMAP  98304u      // 9216 int
#define WS_TPG     137216u     // 9216 f32  -> ends 174080
#define WS_XGT     (1u<<20)    // 72*12*16384 = 14,155,776
#define WS_W1T     (16u<<20)   // 37,748,736 -> ends 54,525,952
#define WS_HBUF    (56u<<20)   // 72*48*16384 = 56,623,104 -> ends 115,343,360
#define WS_W2T     (1u<<20)    // aliases XGT/W1T, written after ffn1

__device__ __forceinline__ void load16_lds(const void* g, void* l) {
  __builtin_amdgcn_global_load_lds(
      (const __attribute__((address_space(1))) void*)g,
      (__attribute__((address_space(3))) void*)l, 16, 0, 0);
}

// ---------------------------------------------------------------------------
// Router: 256 blocks x 32 tokens, wave-per-token (8 tokens/wave).
// Router weights live in 96 VGPRs per lane. Zero global atomics.
// ---------------------------------------------------------------------------
__global__ __launch_bounds__(256) void router3(
    const float* __restrict__ x, const float* __restrict__ Wr,
    float* __restrict__ tprob, int* __restrict__ be_out,
    int* __restrict__ cnt_blk, float* __restrict__ imp_blk)
{
  const int tid = threadIdx.x, lane = tid & 63, wv = tid >> 6;
  const int b = blockIdx.x;
  __shared__ int cnt_l[NEXP];
  __shared__ float imp_l[4][NEXP];
  if (tid < NEXP) cnt_l[tid] = 0;

  // wreg[j*4+q][e] = Wr[c][e], c = j*256 + lane*4 + q
  float wreg[12][8];
  #pragma unroll
  for (int j = 0; j < 3; ++j)
    #pragma unroll
    for (int q = 0; q < 4; ++q) {
      const float4* p = (const float4*)(Wr + (size_t)(j * 256 + lane * 4 + q) * 8);
      float4 lo = p[0], hi = p[1];
      wreg[j*4+q][0] = lo.x; wreg[j*4+q][1] = lo.y;
      wreg[j*4+q][2] = lo.z; wreg[j*4+q][3] = lo.w;
      wreg[j*4+q][4] = hi.x; wreg[j*4+q][5] = hi.y;
      wreg[j*4+q][6] = hi.z; wreg[j*4+q][7] = hi.w;
    }

  float impacc[NEXP];
  #pragma unroll
  for (int e = 0; e < NEXP; ++e) impacc[e] = 0.0f;
  __syncthreads();

  #pragma unroll 1
  for (int t = 0; t < 8; ++t) {
    const int tok = b * 32 + wv * 8 + t;
    float4 xv[3];
    #pragma unroll
    for (int j = 0; j < 3; ++j)
      xv[j] = *(const float4*)(x + (size_t)tok * CDIM + j * 256 + lane * 4);

    float acc[NEXP];
    #pragma unroll
    for (int e = 0; e < NEXP; ++e) acc[e] = 0.0f;
    #pragma unroll
    for (int j = 0; j < 3; ++j) {
      const float xa[4] = {xv[j].x, xv[j].y, xv[j].z, xv[j].w};
      #pragma unroll
      for (int q = 0; q < 4; ++q)
        #pragma unroll
        for (int e = 0; e < NEXP; ++e)
          acc[e] = fmaf(xa[q], wreg[j*4+q][e], acc[e]);
    }
    #pragma unroll
    for (int e = 0; e < NEXP; ++e) {
      float v = acc[e];
      v += __shfl_xor(v, 1);  v += __shfl_xor(v, 2);  v += __shfl_xor(v, 4);
      v += __shfl_xor(v, 8);  v += __shfl_xor(v, 16); v += __shfl_xor(v, 32);
      acc[e] = v;
    }
    float m = acc[0]; int be = 0;
    #pragma unroll
    for (int e = 1; e < NEXP; ++e) if (acc[e] > m) { m = acc[e]; be = e; }
    float pr[NEXP]; float s = 0.0f;
    #pragma unroll
    for (int e = 0; e < NEXP; ++e) { pr[e] = __expf(acc[e] - m); s += pr[e]; }
    const float inv = 1.0f / s;
    #pragma unroll
    for (int e = 0; e < NEXP; ++e) impacc[e] += pr[e] * inv;
    if (lane == 0) {
      tprob[tok]  = pr[be] * inv;
      be_out[tok] = be;
      atomicAdd(&cnt_l[be], 1);          // LDS atomic
    }
  }

  if (lane == 0) {
    #pragma unroll
    for (int e = 0; e < NEXP; ++e) imp_l[wv][e] = impacc[e];
  }
  __syncthreads();
  if (tid < NEXP) {
    cnt_blk[b * NEXP + tid] = cnt_l[tid];
    imp_blk[b * NEXP + tid] =
        imp_l[0][tid] + imp_l[1][tid] + imp_l[2][tid] + imp_l[3][tid];
  }
}

// ---------------------------------------------------------------------------
// Scan: one block, 256 threads. Per-expert exclusive scan over 256 blocks,
// padded offsets, counts, importance, aux loss. No atomics anywhere.
// ---------------------------------------------------------------------------
__global__ __launch_bounds__(256) void scan_kernel(
    const int* __restrict__ cnt_blk, const float* __restrict__ imp_blk,
    int* __restrict__ counts, int* __restrict__ off,
    int* __restrict__ base_blk, float* __restrict__ out_aux)
{
  const int tid = threadIdx.x, lane = tid & 63, wv = tid >> 6;
  __shared__ int   wsum[NEXP][4];
  __shared__ float wimp[NEXP][4];
  __shared__ int   off_s[9];

  int pref[NEXP];
  #pragma unroll
  for (int e = 0; e < NEXP; ++e) {
    int v = cnt_blk[tid * NEXP + e];
    int inc = v;
    #pragma unroll
    for (int o = 1; o < 64; o <<= 1) {
      int n = __shfl_up(inc, o);
      if (lane >= o) inc += n;
    }
    if (lane == 63) wsum[e][wv] = inc;
    pref[e] = inc - v;

    float f = imp_blk[tid * NEXP + e];
    f += __shfl_xor(f, 1);  f += __shfl_xor(f, 2);  f += __shfl_xor(f, 4);
    f += __shfl_xor(f, 8);  f += __shfl_xor(f, 16); f += __shfl_xor(f, 32);
    if (lane == 0) wimp[e][wv] = f;
  }
  __syncthreads();
  if (tid == 0) {
    int o = 0; float aux = 0.0f;
    #pragma unroll
    for (int e = 0; e < NEXP; ++e) {
      int tot = wsum[e][0] + wsum[e][1] + wsum[e][2] + wsum[e][3];
      float im = wimp[e][0] + wimp[e][1] + wimp[e][2] + wimp[e][3];
      counts[e] = tot;
      aux += im * (float)tot;
      off_s[e] = o;
      o += (tot + 127) & ~127;
    }
    off_s[8] = o;
    out_aux[0] = (float)NEXP * aux / ((float)N_TOK * (float)N_TOK);
    for (int i = 0; i < 9; ++i) off[i] = off_s[i];
  }
  __syncthreads();
  #pragma unroll
  for (int e = 0; e < NEXP; ++e) {
    int wofs = 0;
    #pragma unroll
    for (int w = 0; w < 4; ++w) if (w < wv) wofs += wsum[e][w];
    base_blk[tid * NEXP + e] = off_s[e] + wofs + pref[e];
  }
}

// ---------------------------------------------------------------------------
// Gather: same 32-token blocking as router. Slot = scanned base + ballot rank
// (deterministic). Packs rows into xgT [tile][kc:12][128][64] swizzled bf16.
// ---------------------------------------------------------------------------
__global__ __launch_bounds__(256) void gather2(
    const float* __restrict__ x, const float* __restrict__ tprob,
    const int* __restrict__ be, const int* __restrict__ base_blk,
    bf16* __restrict__ xgT, int* __restrict__ tokmap, float* __restrict__ tpg)
{
  const int tid = threadIdx.x, lane = tid & 63, wv = tid >> 6;
  const int b = blockIdx.x;
  __shared__ int slot_l[32];

  if (wv == 0) {
    const int t = lane;
    const int bet = (t < 32) ? be[b * 32 + t] : -1;
    int slot = -1;
    #pragma unroll
    for (int e = 0; e < NEXP; ++e) {
      unsigned long long msk = __ballot(bet == e);
      if (bet == e) {
        int rank = __popcll(msk & ((1ull << lane) - 1ull));
        slot = base_blk[b * NEXP + e] + rank;
      }
    }
    if (t < 32) {
      slot_l[t] = slot;
      const int tok = b * 32 + t;
      tokmap[slot] = tok;
      tpg[slot] = tprob[tok];
    }
  }
  __syncthreads();

  #pragma unroll 1
  for (int t8 = 0; t8 < 8; ++t8) {
    const int t = wv * 8 + t8;
    const int slot = slot_l[t];
    const int tok = b * 32 + t;
    const int tile = slot >> 7, r = slot & 127;
    #pragma unroll
    for (int j = 0; j < 3; ++j) {
      const int col = j * 256 + lane * 4;
      const int kc = col >> 6, cw = col & 63;
      float4 v = *(const float4*)(x + (size_t)tok * CDIM + col);
      bf16x4 o;
      o[0] = (bf16)v.x; o[1] = (bf16)v.y; o[2] = (bf16)v.z; o[3] = (bf16)v.w;
      char* dst = (char*)xgT + (((size_t)tile * 12 + kc) * 128 + r) * 128
                  + ((cw * 2) ^ ((r & 7) << 4));
      *(bf16x4*)dst = o;
    }
  }
}

// ---------------------------------------------------------------------------
// W [E][R][S] fp32 -> tiled bf16 [E][S/64][R/64][64][64], swizzled rows.
// ---------------------------------------------------------------------------
__global__ __launch_bounds__(256) void transpose_w(
    const float* __restrict__ W, bf16* __restrict__ WT, int R, int S)
{
  __shared__ float t[64][65];
  const int r0 = blockIdx.x * 64, s0 = blockIdx.y * 64, e = blockIdx.z;
  const float* We = W + (size_t)e * R * S;
  const int NT = S >> 6, NK = R >> 6;
  char* outT = (char*)WT + (((size_t)e * NT + (s0 >> 6)) * NK + (r0 >> 6)) * 8192;
  const int tid = threadIdx.x, lr = tid >> 4, lc4 = tid & 15;

  #pragma unroll
  for (int j = 0; j < 4; ++j) {
    int r = lr + j * 16;
    float4 v = *(const float4*)(We + (size_t)(r0 + r) * S + s0 + lc4 * 4);
    t[r][lc4 * 4 + 0] = v.x; t[r][lc4 * 4 + 1] = v.y;
    t[r][lc4 * 4 + 2] = v.z; t[r][lc4 * 4 + 3] = v.w;
  }
  __syncthreads();
  #pragma unroll
  for (int j = 0; j < 4; ++j) {
    int sI = lr + j * 16;
    bf16x4 o;
    #pragma unroll
    for (int q = 0; q < 4; ++q) o[q] = (bf16)t[lc4 * 4 + q][sI];
    *(bf16x4*)(outT + sI * 128 + ((lc4 * 8) ^ ((sI & 7) << 4))) = o;
  }
}

// ---------------------------------------------------------------------------
// Grouped GEMM, m97 structure: BM=128, BN=128|64, BK=64, 4 waves,
// single-buffer LDS, 2 barriers per K-step. __launch_bounds__(256,3)
// forces <=170 unified regs -> 3 waves/SIMD (3 blocks/CU co-resident).
// XCD-chunked tile remap: bid%8 owns a contiguous 9-wide x-range.
// ---------------------------------------------------------------------------
template<int NKC, int NCHN, int BN, bool GELU>
__global__ __launch_bounds__(256, 3) void ffn_t(
    const bf16* __restrict__ Abuf, const bf16* __restrict__ Wt,
    const float* __restrict__ bias, const int* __restrict__ off,
    const int* __restrict__ tokmap, const float* __restrict__ tpg,
    bf16* __restrict__ hbufT, float* __restrict__ y)
{
  constexpr int NC = BN / 64;         // 64-col chunks per block (1 or 2)
  constexpr int FN = BN / 32;         // per-wave N fragments (2 or 4)
  constexpr int NYT = NCHN / NC;      // y-tiles in grid

  // XCD-aware remap: bid%8 = XCD chunk; chunk covers x in [9c, 9c+9) x all y.
  const int bid = blockIdx.x + blockIdx.y * 72;
  const int c  = bid & 7;
  const int r2 = bid >> 3;
  const int bx = c * 9 + (r2 % 9);
  const int by = r2 / 9;
  (void)NYT;

  const int ptot = off[8];
  const int m0 = bx * 128;
  if (m0 >= ptot) return;
  int e = 0;
  #pragma unroll
  for (int q = 0; q < 7; ++q) if (m0 >= off[q + 1]) e = q + 1;

  const int tid = threadIdx.x, lane = tid & 63, wv = tid >> 6;
  const int wr = (wv >> 1) * 64;           // wave row
  const int wc = (wv & 1) * (BN / 2);      // wave col

  __shared__ __attribute__((aligned(1024))) char smem[32768];
  // A tile @0 (16K), B tile @16K (BN*128 bytes)

  const char* aBase = (const char*)Abuf + (size_t)bx * NKC * 16384;
  // per-wave B stage source: rows [wv*(BN/4), +BN/4) of the BN x 64 tile
  const int brow0 = wv * (BN / 4);
  const char* bBase0 = (const char*)Wt +
      (((size_t)e * NCHN + by * NC + (brow0 >> 6)) * NKC) * 8192
      + (brow0 & 63) * 128;

  f32x4 acc[4][FN];
  #pragma unroll
  for (int i = 0; i < 4; ++i)
    #pragma unroll
    for (int j = 0; j < FN; ++j)
      #pragma unroll
      for (int q = 0; q < 4; ++q) acc[i][j][q] = 0.0f;

  for (int kc = 0; kc < NKC; ++kc) {
    __syncthreads();   // previous compute done reading smem
    {
      const char* aS = aBase + (size_t)kc * 16384 + wv * 4096 + lane * 16;
      const char* bS = bBase0 + (size_t)kc * 8192 + lane * 16;
      #pragma unroll
      for (int i = 0; i < 4; ++i)
        load16_lds(aS + i * 1024, smem + wv * 4096 + i * 1024);
      #pragma unroll
      for (int i = 0; i < BN / 32; ++i)
        load16_lds(bS + i * 1024, smem + 16384 + brow0 * 128 + i * 1024);
    }
    __syncthreads();   // vmcnt(0) drain: tile resident
    #pragma unroll
    for (int kk = 0; kk < 2; ++kk) {
      bf16x8 af[4], bfr[FN];
      #pragma unroll
      for (int f = 0; f < 4; ++f) {
        int row  = wr + f * 16 + (lane & 15);
        int byte = row * 128 + kk * 64 + (lane >> 4) * 16;
        byte ^= (row & 7) << 4;
        af[f] = *(const bf16x8*)(smem + byte);
      }
      #pragma unroll
      for (int f = 0; f < FN; ++f) {
        int row  = wc + f * 16 + (lane & 15);
        int byte = row * 128 + kk * 64 + (lane >> 4) * 16;
        byte ^= (row & 7) << 4;
        bfr[f] = *(const bf16x8*)(smem + 16384 + byte);
      }
      #pragma unroll
      for (int fm = 0; fm < 4; ++fm)
        #pragma unroll
        for (int fn = 0; fn < FN; ++fn)
          acc[fm][fn] = __builtin_amdgcn_mfma_f32_16x16x32_bf16(
              af[fm], bfr[fn], acc[fm][fn], 0, 0, 0);
    }
  }
  __syncthreads();     // all ds_reads done before epilogue reuses smem

  const int g = lane >> 4, ci = lane & 15;
  float bv[FN];
  #pragma unroll
  for (int fn = 0; fn < FN; ++fn)
    bv[fn] = bias[e * (NCHN * 64) + by * BN + wc + fn * 16 + ci];

  if (GELU) {
    // bias + tanh-GELU -> swizzled bf16 C tile (exactly 32 KB) -> linear copy
    #pragma unroll
    for (int fm = 0; fm < 4; ++fm)
      #pragma unroll
      for (int fn = 0; fn < FN; ++fn)
        #pragma unroll
        for (int rg = 0; rg < 4; ++rg) {
          int row = wr + fm * 16 + g * 4 + rg;
          int col = wc + fn * 16 + ci;
          float v = acc[fm][fn][rg] + bv[fn];
          float t3 = v + 0.044715f * v * v * v;
          float gel = v / (1.0f + __expf(-1.5957691216f * t3));
          int chunk = col >> 6, cw = col & 63;
          int byte = chunk * 16384 + row * 128 + ((cw * 2) ^ ((row & 7) << 4));
          *(bf16*)(smem + byte) = (bf16)gel;
        }
    __syncthreads();
    char* hdst = (char*)hbufT + ((size_t)bx * 48 + by * 2) * 16384;
    #pragma unroll
    for (int i = 0; i < 8; ++i) {
      int bo = (i * 256 + tid) * 16;
      *(f32x4*)(hdst + bo) = *(const f32x4*)(smem + bo);
    }
  } else {
    // bias + tprob -> f32 tile [128][BN] in LDS -> coalesced row scatter
    float tp[4][4];
    #pragma unroll
    for (int fm = 0; fm < 4; ++fm)
      #pragma unroll
      for (int rg = 0; rg < 4; ++rg)
        tp[fm][rg] = tpg[m0 + wr + fm * 16 + g * 4 + rg];
    float* smemf = (float*)smem;
    // BN=64: 128x64 f32 = 32 KB, single phase.
    #pragma unroll
    for (int fm = 0; fm < 4; ++fm)
      #pragma unroll
      for (int fn = 0; fn < FN; ++fn)
        #pragma unroll
        for (int rg = 0; rg < 4; ++rg) {
          int row = wr + fm * 16 + g * 4 + rg;
          int col = wc + fn * 16 + ci;
          smemf[row * BN + col] = (acc[fm][fn][rg] + bv[fn]) * tp[fm][rg];
        }
    __syncthreads();
    // 128 rows x (BN/4) f32x4, (128*BN/4)/256 per thread
    #pragma unroll
    for (int it = 0; it < BN / 8; ++it) {
      int lin = it * 256 + tid;
      int row = lin / (BN / 4);
      int c4  = lin % (BN / 4);
      int tokr = tokmap[m0 + row];
      f32x4 v = *(const f32x4*)(smemf + row * BN + c4 * 4);
      if (tokr >= 0)
        *(f32x4*)(y + (size_t)tokr * CDIM + by * BN + c4 * 4) = v;
    }
  }
}

// ---------------------------------------------------------------------------
extern "C" void kernel_launch(void* const* d_in, const int* in_sizes, int n_in,
                              void* d_out, int out_size, void* d_ws, size_t ws_size,
                              hipStream_t stream)
{
  const float* x  = (const float*)d_in[0];
  const float* Wr = (const float*)d_in[1];
  const float* W1 = (const float*)d_in[2];
  const float* b1 = (const float*)d_in[3];
  const float* W2 = (const float*)d_in[4];
  const float* b2 = (const float*)d_in[5];
  float* out = (float*)d_out;

  char* ws = (char*)d_ws;
  int*   be         = (int*)(ws + WS_BE);
  float* tprob      = (float*)(ws + WS_TPROB);
  int*   cnt_blk    = (int*)(ws + WS_CNTB);
  float* imp_blk    = (float*)(ws + WS_IMPB);
  int*   base_blk   = (int*)(ws + WS_BASEB);
  int*   counts     = (int*)(ws + WS_CNT);
  int*   off        = (int*)(ws + WS_OFF);
  int*   tokmap     = (int*)(ws + WS_TOKMAP);
  float* tpg        = (float*)(ws + WS_TPG);
  bf16*  xgT        = (bf16*)(ws + WS_XGT);
  bf16*  w1tT       = (bf16*)(ws + WS_W1T);
  bf16*  hbufT      = (bf16*)(ws + WS_HBUF);
  bf16*  w2tT       = (bf16*)(ws + WS_W2T);   // written after ffn1

  hipMemsetAsync(tokmap, 0xFF, 9216 * sizeof(int), stream);

  router3<<<dim3(NBLK), 256, 0, stream>>>(x, Wr, tprob, be, cnt_blk, imp_blk);
  scan_kernel<<<dim3(1), 256, 0, stream>>>(cnt_blk, imp_blk, counts, off,
                                           base_blk, out + (size_t)N_TOK * CDIM);
  gather2<<<dim3(NBLK), 256, 0, stream>>>(x, tprob, be, base_blk,
                                          xgT, tokmap, tpg);
  transpose_w<<<dim3(CDIM / 64, HDIM / 64, NEXP), 256, 0, stream>>>(
      W1, w1tT, CDIM, HDIM);
  ffn_t<12, 48, 128, true><<<dim3(72, 24), 256, 0, stream>>>(
      xgT, w1tT, b1, off, tokmap, tpg, hbufT, nullptr);
  transpose_w<<<dim3(HDIM / 64, CDIM / 64, NEXP), 256, 0, stream>>>(
      W2, w2tT, HDIM, CDIM);
  ffn_t<48, 12, 64, false><<<dim3(72, 12), 256, 0, stream>>>(
      hbufT, w2tT, b2, off, tokmap, tpg, nullptr, out);
}